// Round 2
// baseline (1482.515 us; speedup 1.0000x reference)
//
#include <hip/hip_runtime.h>
#include <cstddef>

#define B_   64
#define N_   512
#define NV_  32768
#define NE_  8192
#define NNZ_ 262144
#define SNNZ_ 24576
#define D_   300
#define HID_ 256
#define NC_  10

// ---------------- generic scatter-add ------------------------------------------------
// dst[sidx[w]][0:dim] += vals[w] * (gscale?gscale[gidx[w]]:1) * src[row(gidx[w])][0:dim]
// where row(g) = xidx ? xidx[g] : g   (xidx folds the embedding lookup for layer 1)
__global__ __launch_bounds__(256) void scatter_kernel(const int* gidx, const int* sidx,
                                                      const float* vals, const float* gscale,
                                                      const int* xidx,
                                                      const float* src, int dim, int sstride,
                                                      float* dst, int dstride, int nnz) {
    int w = (blockIdx.x * 256 + threadIdx.x) >> 6;
    int lane = threadIdx.x & 63;
    if (w >= nnz) return;
    int g = gidx[w];
    int s = sidx[w];
    float val = vals[w];
    if (gscale) val *= gscale[g];
    int grow = xidx ? xidx[g] : g;
    const float* srow = src + (size_t)grow * sstride;
    float* drow = dst + (size_t)s * dstride;
    for (int d = lane; d < dim; d += 64)
        atomicAdd(&drow[d], val * srow[d]);
}

// ---------------- f32 tiled GEMM + deg scale + bias + relu -------------------------
// C[v][j] = relu(degv[v] * sum_k A[v][k]*W[k][j] + bias[j]),  W row-major [K][256]
__global__ __launch_bounds__(256) void gemm_relu_kernel(const float* A, int lda, int K,
                                                        const float* W, const float* bias,
                                                        const float* degv, float* C) {
    __shared__ float As[16][64];
    __shared__ float Ws[16][68];
    int bm0 = blockIdx.x * 64;
    int bn0 = blockIdx.y * 64;
    int tid = threadIdx.x;
    int tx = tid & 15, ty = tid >> 4;
    int amr = tid >> 2, akc = (tid & 3) * 4;
    int wkr = tid >> 4, wnc = (tid & 15) * 4;
    float acc[4][4] = {};
    int ktiles = (K + 15) / 16;
    const float* Arow = A + (size_t)(bm0 + amr) * lda + akc;
    for (int kt = 0; kt < ktiles; ++kt) {
        int k0 = kt * 16;
        float4 av = *reinterpret_cast<const float4*>(Arow + k0);
        As[akc + 0][amr] = av.x;
        As[akc + 1][amr] = av.y;
        As[akc + 2][amr] = av.z;
        As[akc + 3][amr] = av.w;
        int krow = k0 + wkr;
        float4 wv = make_float4(0.f, 0.f, 0.f, 0.f);
        if (krow < K)
            wv = *reinterpret_cast<const float4*>(W + (size_t)krow * HID_ + bn0 + wnc);
        Ws[wkr][wnc + 0] = wv.x; Ws[wkr][wnc + 1] = wv.y;
        Ws[wkr][wnc + 2] = wv.z; Ws[wkr][wnc + 3] = wv.w;
        __syncthreads();
#pragma unroll
        for (int k = 0; k < 16; ++k) {
            float4 a = *reinterpret_cast<const float4*>(&As[k][ty * 4]);
            float4 w = *reinterpret_cast<const float4*>(&Ws[k][tx * 4]);
            acc[0][0] += a.x * w.x; acc[0][1] += a.x * w.y; acc[0][2] += a.x * w.z; acc[0][3] += a.x * w.w;
            acc[1][0] += a.y * w.x; acc[1][1] += a.y * w.y; acc[1][2] += a.y * w.z; acc[1][3] += a.y * w.w;
            acc[2][0] += a.z * w.x; acc[2][1] += a.z * w.y; acc[2][2] += a.z * w.z; acc[2][3] += a.z * w.w;
            acc[3][0] += a.w * w.x; acc[3][1] += a.w * w.y; acc[3][2] += a.w * w.z; acc[3][3] += a.w * w.w;
        }
        __syncthreads();
    }
#pragma unroll
    for (int i = 0; i < 4; ++i) {
        int row = bm0 + ty * 4 + i;
        float dv = degv[row];
#pragma unroll
        for (int j = 0; j < 4; ++j) {
            int col = bn0 + tx * 4 + j;
            float v = acc[i][j] * dv + bias[col];
            C[(size_t)row * HID_ + col] = v > 0.f ? v : 0.f;
        }
    }
}

// ---------------- attention logits: e[v] = h[row(v)].attW[:dim] + tfidf[v].attW[dim:] + attb
__global__ __launch_bounds__(256) void logits_kernel(const float* h, int dim, int stride,
                                                     const int* xidx,
                                                     const float* tfidf, const float* attW,
                                                     const float* attb, float* e) {
    int w = (blockIdx.x * 256 + threadIdx.x) >> 6;
    int lane = threadIdx.x & 63;
    if (w >= NV_) return;
    int row = xidx ? xidx[w] : w;
    const float* hp = h + (size_t)row * stride;
    float s = 0.f;
    for (int d = lane; d < dim; d += 64) s += hp[d] * attW[d];
#pragma unroll
    for (int off = 32; off > 0; off >>= 1) s += __shfl_down(s, off);
    if (lane == 0) {
        s += tfidf[w * 2] * attW[dim] + tfidf[w * 2 + 1] * attW[dim + 1] + attb[0];
        e[w] = s;
    }
}

// ---------------- global max of e ---------------------------------------------------
__global__ __launch_bounds__(1024) void gmax_kernel(const float* e, float* gmax) {
    __shared__ float red[1024];
    float m = -3.4e38f;
    for (int i = threadIdx.x; i < NV_; i += 1024) m = fmaxf(m, e[i]);
    red[threadIdx.x] = m;
    __syncthreads();
    for (int s = 512; s > 0; s >>= 1) {
        if (threadIdx.x < (unsigned)s) red[threadIdx.x] = fmaxf(red[threadIdx.x], red[threadIdx.x + s]);
        __syncthreads();
    }
    if (threadIdx.x == 0) gmax[0] = red[0];
}

// ---------------- per-graph pooling: p[b][0:dim]=attn-pool, p[b][dim:2dim]=maxpool ---
__global__ __launch_bounds__(256) void pool_kernel(const float* h, int dim, int stride,
                                                   const int* xidx,
                                                   const float* e, const float* gmax,
                                                   float* p) {
    int b = blockIdx.x;
    __shared__ float w[N_];
    __shared__ int rows[N_];
    __shared__ float red[256];
    float gm = gmax[0];
    float local = 0.f;
    for (int v = threadIdx.x; v < N_; v += 256) {
        int node = b * N_ + v;
        float wv = expf(e[node] - gm);
        w[v] = wv;
        rows[v] = xidx ? xidx[node] : node;
        local += wv;
    }
    red[threadIdx.x] = local;
    __syncthreads();
    for (int s = 128; s > 0; s >>= 1) {
        if (threadIdx.x < (unsigned)s) red[threadIdx.x] += red[threadIdx.x + s];
        __syncthreads();
    }
    float inv = 1.0f / (red[0] + 1e-10f);
    for (int d = threadIdx.x; d < dim; d += 256) {
        float acc = 0.f, mx = -3.4e38f;
        for (int v = 0; v < N_; ++v) {
            float xx = h[(size_t)rows[v] * stride + d];
            acc += w[v] * xx;
            mx = fmaxf(mx, xx);
        }
        p[(size_t)b * 2 * dim + d] = acc * inv;
        p[(size_t)b * 2 * dim + dim + d] = mx;
    }
}

// ---------------- final prediction ---------------------------------------------------
__global__ __launch_bounds__(64) void final_kernel(const float* p0, const float* p1, const float* p2,
                                                   const float* pW0, const float* pb0,
                                                   const float* pW1, const float* pb1,
                                                   const float* pW2, const float* pb2, float* out) {
    int b = blockIdx.x;
    int c = threadIdx.x;
    if (c >= NC_) return;
    float s = pb0[c] + pb1[c] + pb2[c];
    for (int k = 0; k < 2 * D_; ++k) s += p0[(size_t)b * 2 * D_ + k] * pW0[k * NC_ + c];
    for (int k = 0; k < 2 * HID_; ++k) s += p1[(size_t)b * 2 * HID_ + k] * pW1[k * NC_ + c];
    for (int k = 0; k < 2 * HID_; ++k) s += p2[(size_t)b * 2 * HID_ + k] * pW2[k * NC_ + c];
    out[b * NC_ + c] = s;
}

extern "C" void kernel_launch(void* const* d_in, const int* in_sizes, int n_in,
                              void* d_out, int out_size, void* d_ws, size_t ws_size,
                              hipStream_t stream) {
    const int*   x         = (const int*)d_in[0];
    const int*   inc_rows  = (const int*)d_in[1];
    const int*   inc_cols  = (const int*)d_in[2];
    const float* inc_vals  = (const float*)d_in[3];
    const int*   sent_rows = (const int*)d_in[4];
    const int*   sent_cols = (const int*)d_in[5];
    const float* sent_vals = (const float*)d_in[6];
    const float* deg_v     = (const float*)d_in[7];
    const float* deg_e     = (const float*)d_in[8];
    // d_in[9] graph_ids = v // N_, d_in[10] max_pool_idx = arange -> structural, unused
    const float* tf_idf = (const float*)d_in[11];
    const float* emb    = (const float*)d_in[12];
    const float* W1 = (const float*)d_in[13];
    const float* b1 = (const float*)d_in[14];
    const float* W2 = (const float*)d_in[15];
    const float* b2 = (const float*)d_in[16];
    const float* attW0 = (const float*)d_in[17];
    const float* attb0 = (const float*)d_in[18];
    const float* attW1 = (const float*)d_in[19];
    const float* attb1 = (const float*)d_in[20];
    const float* attW2 = (const float*)d_in[21];
    const float* attb2 = (const float*)d_in[22];
    const float* pW0 = (const float*)d_in[23];
    const float* pb0 = (const float*)d_in[24];
    const float* pW1 = (const float*)d_in[25];
    const float* pb1 = (const float*)d_in[26];
    const float* pW2 = (const float*)d_in[27];
    const float* pb2 = (const float*)d_in[28];
    float* out = (float*)d_out;

    // workspace layout
    char* ws = (char*)d_ws;
    size_t off = 0;
    auto alloc = [&](size_t bytes) {
        void* p = ws + off;
        off += (bytes + 255) & ~(size_t)255;
        return p;
    };
    float* hv = (float*)alloc((size_t)NV_ * 304 * sizeof(float)); // padded stride for K=300
    float* m  = (float*)alloc((size_t)NE_ * D_ * sizeof(float));
    float* m2 = (float*)alloc((size_t)NE_ * D_ * sizeof(float));
    float* h1 = (float*)alloc((size_t)NV_ * HID_ * sizeof(float));
    float* h2 = (float*)alloc((size_t)NV_ * HID_ * sizeof(float));
    float* e  = (float*)alloc((size_t)NV_ * sizeof(float));
    float* gmax = (float*)alloc(256);
    float* p0 = (float*)alloc((size_t)B_ * 2 * D_ * sizeof(float));
    float* p1 = (float*)alloc((size_t)B_ * 2 * HID_ * sizeof(float));
    float* p2 = (float*)alloc((size_t)B_ * 2 * HID_ * sizeof(float));

    // ---- layer 1 (input = emb[x], dim 300) ----
    hipMemsetAsync(m, 0, (size_t)NE_ * D_ * sizeof(float), stream);
    scatter_kernel<<<NNZ_ / 4, 256, 0, stream>>>(
        inc_rows, inc_cols, inc_vals, nullptr, x, emb, D_, D_, m, D_, NNZ_);
    hipMemsetAsync(m2, 0, (size_t)NE_ * D_ * sizeof(float), stream);
    scatter_kernel<<<SNNZ_ / 4, 256, 0, stream>>>(
        sent_rows, sent_cols, sent_vals, deg_e, nullptr, m, D_, D_, m2, D_, SNNZ_);
    hipMemsetAsync(hv, 0, (size_t)NV_ * 304 * sizeof(float), stream);
    scatter_kernel<<<NNZ_ / 4, 256, 0, stream>>>(
        inc_cols, inc_rows, inc_vals, nullptr, nullptr, m2, D_, D_, hv, 304, NNZ_);
    {
        dim3 grid(NV_ / 64, HID_ / 64);
        gemm_relu_kernel<<<grid, 256, 0, stream>>>(hv, 304, D_, W1, b1, deg_v, h1);
    }

    // ---- layer 2 (input = h1, dim 256) ----
    hipMemsetAsync(m, 0, (size_t)NE_ * HID_ * sizeof(float), stream);
    scatter_kernel<<<NNZ_ / 4, 256, 0, stream>>>(
        inc_rows, inc_cols, inc_vals, nullptr, nullptr, h1, HID_, HID_, m, HID_, NNZ_);
    hipMemsetAsync(m2, 0, (size_t)NE_ * HID_ * sizeof(float), stream);
    scatter_kernel<<<SNNZ_ / 4, 256, 0, stream>>>(
        sent_rows, sent_cols, sent_vals, deg_e, nullptr, m, HID_, HID_, m2, HID_, SNNZ_);
    hipMemsetAsync(hv, 0, (size_t)NV_ * HID_ * sizeof(float), stream);
    scatter_kernel<<<NNZ_ / 4, 256, 0, stream>>>(
        inc_cols, inc_rows, inc_vals, nullptr, nullptr, m2, HID_, HID_, hv, HID_, NNZ_);
    {
        dim3 grid(NV_ / 64, HID_ / 64);
        gemm_relu_kernel<<<grid, 256, 0, stream>>>(hv, HID_, HID_, W2, b2, deg_v, h2);
    }

    // ---- pools ----
    logits_kernel<<<NV_ / 4, 256, 0, stream>>>(emb, D_, D_, x, tf_idf, attW0, attb0, e);
    gmax_kernel<<<1, 1024, 0, stream>>>(e, gmax);
    pool_kernel<<<B_, 256, 0, stream>>>(emb, D_, D_, x, e, gmax, p0);

    logits_kernel<<<NV_ / 4, 256, 0, stream>>>(h1, HID_, HID_, nullptr, tf_idf, attW1, attb1, e);
    gmax_kernel<<<1, 1024, 0, stream>>>(e, gmax);
    pool_kernel<<<B_, 256, 0, stream>>>(h1, HID_, HID_, nullptr, e, gmax, p1);

    logits_kernel<<<NV_ / 4, 256, 0, stream>>>(h2, HID_, HID_, nullptr, tf_idf, attW2, attb2, e);
    gmax_kernel<<<1, 1024, 0, stream>>>(e, gmax);
    pool_kernel<<<B_, 256, 0, stream>>>(h2, HID_, HID_, nullptr, e, gmax, p2);

    // ---- final linear ----
    final_kernel<<<B_, 64, 0, stream>>>(p0, p1, p2, pW0, pb0, pW1, pb1, pW2, pb2, out);
}

// Round 3
// 814.435 us; speedup vs baseline: 1.8203x; 1.8203x over previous
//
#include <hip/hip_runtime.h>
#include <cstddef>

#define B_   64
#define N_   512
#define NV_  32768
#define NE_  8192
#define NNZ_ 262144
#define SNNZ_ 24576
#define D_   300
#define HID_ 256
#define NC_  10

// ---------------- CSR build: histogram -> exclusive scan -> placement ---------------
__global__ __launch_bounds__(256) void hist_kernel(const int* __restrict__ keys, int n,
                                                   int* __restrict__ cnt) {
    int i = blockIdx.x * 256 + threadIdx.x;
    if (i < n) atomicAdd(&cnt[keys[i]], 1);
}

// single block, n multiple of 1024
__global__ __launch_bounds__(1024) void scan_kernel(const int* __restrict__ cnt, int n,
                                                    int* __restrict__ rowptr,
                                                    int* __restrict__ fill) {
    __shared__ int part[1024];
    int t = threadIdx.x;
    int per = n / 1024;
    int base = t * per;
    int s = 0;
    for (int i = 0; i < per; ++i) s += cnt[base + i];
    part[t] = s;
    __syncthreads();
    for (int off = 1; off < 1024; off <<= 1) {
        int add = (t >= off) ? part[t - off] : 0;
        __syncthreads();
        part[t] += add;
        __syncthreads();
    }
    int run = (t > 0) ? part[t - 1] : 0;
    for (int i = 0; i < per; ++i) {
        rowptr[base + i] = run;
        fill[base + i] = run;
        run += cnt[base + i];
    }
    if (t == 1023) rowptr[n] = run;
}

__global__ __launch_bounds__(256) void place_kernel(const int* __restrict__ keys,
                                                    const int* __restrict__ other,
                                                    const float* __restrict__ vals, int n,
                                                    int* __restrict__ fill,
                                                    int* __restrict__ osrc,
                                                    float* __restrict__ oval) {
    int i = blockIdx.x * 256 + threadIdx.x;
    if (i >= n) return;
    int k = keys[i];
    int p = atomicAdd(&fill[k], 1);
    osrc[p] = other[i];
    oval[p] = vals[i];
}

// ---------------- segment gather-sum (one wave per segment) -------------------------
// dst[seg][0:DIM] = (gscale?gscale[seg]:1) * sum_k vals[k] * src[row(srcidx[k])][0:DIM]
template <int DIM>
__global__ __launch_bounds__(256) void gather_kernel(const int* __restrict__ rowptr,
                                                     const int* __restrict__ srcidx,
                                                     const float* __restrict__ svals,
                                                     const int* __restrict__ xidx,
                                                     const float* __restrict__ src, int sstride,
                                                     const float* __restrict__ gscale,
                                                     float* __restrict__ dst, int dstride,
                                                     int nseg) {
    int seg = (blockIdx.x * 256 + threadIdx.x) >> 6;
    int lane = threadIdx.x & 63;
    if (seg >= nseg) return;
    int start = rowptr[seg], end = rowptr[seg + 1];
    constexpr int NACC = (DIM + 63) / 64;
    float acc[NACC] = {};
    for (int k = start; k < end; ++k) {
        int r = srcidx[k];
        if (xidx) r = xidx[r];
        float v = svals[k];
        const float* srow = src + (size_t)r * sstride;
#pragma unroll
        for (int i = 0; i < NACC; ++i) {
            int d = i * 64 + lane;
            if (DIM % 64 == 0 || d < DIM) acc[i] += v * srow[d];
        }
    }
    float sc = gscale ? gscale[seg] : 1.f;
    float* drow = dst + (size_t)seg * dstride;
#pragma unroll
    for (int i = 0; i < NACC; ++i) {
        int d = i * 64 + lane;
        if (DIM % 64 == 0 || d < DIM) drow[d] = sc * acc[i];
    }
}

// ---------------- f32 tiled GEMM + deg scale + bias + relu -------------------------
// C[v][j] = relu(degv[v] * sum_k A[v][k]*W[k][j] + bias[j]),  W row-major [K][256]
__global__ __launch_bounds__(256) void gemm_relu_kernel(const float* A, int lda, int K,
                                                        const float* W, const float* bias,
                                                        const float* degv, float* C) {
    __shared__ float As[16][64];
    __shared__ float Ws[16][68];
    int bm0 = blockIdx.x * 64;
    int bn0 = blockIdx.y * 64;
    int tid = threadIdx.x;
    int tx = tid & 15, ty = tid >> 4;
    int amr = tid >> 2, akc = (tid & 3) * 4;
    int wkr = tid >> 4, wnc = (tid & 15) * 4;
    float acc[4][4] = {};
    int ktiles = (K + 15) / 16;
    const float* Arow = A + (size_t)(bm0 + amr) * lda + akc;
    for (int kt = 0; kt < ktiles; ++kt) {
        int k0 = kt * 16;
        float4 av = *reinterpret_cast<const float4*>(Arow + k0);
        As[akc + 0][amr] = av.x;
        As[akc + 1][amr] = av.y;
        As[akc + 2][amr] = av.z;
        As[akc + 3][amr] = av.w;
        int krow = k0 + wkr;
        float4 wv = make_float4(0.f, 0.f, 0.f, 0.f);
        if (krow < K)
            wv = *reinterpret_cast<const float4*>(W + (size_t)krow * HID_ + bn0 + wnc);
        Ws[wkr][wnc + 0] = wv.x; Ws[wkr][wnc + 1] = wv.y;
        Ws[wkr][wnc + 2] = wv.z; Ws[wkr][wnc + 3] = wv.w;
        __syncthreads();
#pragma unroll
        for (int k = 0; k < 16; ++k) {
            float4 a = *reinterpret_cast<const float4*>(&As[k][ty * 4]);
            float4 w = *reinterpret_cast<const float4*>(&Ws[k][tx * 4]);
            acc[0][0] += a.x * w.x; acc[0][1] += a.x * w.y; acc[0][2] += a.x * w.z; acc[0][3] += a.x * w.w;
            acc[1][0] += a.y * w.x; acc[1][1] += a.y * w.y; acc[1][2] += a.y * w.z; acc[1][3] += a.y * w.w;
            acc[2][0] += a.z * w.x; acc[2][1] += a.z * w.y; acc[2][2] += a.z * w.z; acc[2][3] += a.z * w.w;
            acc[3][0] += a.w * w.x; acc[3][1] += a.w * w.y; acc[3][2] += a.w * w.z; acc[3][3] += a.w * w.w;
        }
        __syncthreads();
    }
#pragma unroll
    for (int i = 0; i < 4; ++i) {
        int row = bm0 + ty * 4 + i;
        float dv = degv[row];
#pragma unroll
        for (int j = 0; j < 4; ++j) {
            int col = bn0 + tx * 4 + j;
            float v = acc[i][j] * dv + bias[col];
            C[(size_t)row * HID_ + col] = v > 0.f ? v : 0.f;
        }
    }
}

// ---------------- attention logits ---------------------------------------------------
__global__ __launch_bounds__(256) void logits_kernel(const float* h, int dim, int stride,
                                                     const int* xidx,
                                                     const float* tfidf, const float* attW,
                                                     const float* attb, float* e) {
    int w = (blockIdx.x * 256 + threadIdx.x) >> 6;
    int lane = threadIdx.x & 63;
    if (w >= NV_) return;
    int row = xidx ? xidx[w] : w;
    const float* hp = h + (size_t)row * stride;
    float s = 0.f;
    for (int d = lane; d < dim; d += 64) s += hp[d] * attW[d];
#pragma unroll
    for (int off = 32; off > 0; off >>= 1) s += __shfl_down(s, off);
    if (lane == 0) {
        s += tfidf[w * 2] * attW[dim] + tfidf[w * 2 + 1] * attW[dim + 1] + attb[0];
        e[w] = s;
    }
}

// ---------------- global max of e ---------------------------------------------------
__global__ __launch_bounds__(1024) void gmax_kernel(const float* e, float* gmax) {
    __shared__ float red[1024];
    float m = -3.4e38f;
    for (int i = threadIdx.x; i < NV_; i += 1024) m = fmaxf(m, e[i]);
    red[threadIdx.x] = m;
    __syncthreads();
    for (int s = 512; s > 0; s >>= 1) {
        if (threadIdx.x < (unsigned)s) red[threadIdx.x] = fmaxf(red[threadIdx.x], red[threadIdx.x + s]);
        __syncthreads();
    }
    if (threadIdx.x == 0) gmax[0] = red[0];
}

// ---------------- per-graph pooling --------------------------------------------------
__global__ __launch_bounds__(256) void pool_kernel(const float* h, int dim, int stride,
                                                   const int* xidx,
                                                   const float* e, const float* gmax,
                                                   float* p) {
    int b = blockIdx.x;
    __shared__ float w[N_];
    __shared__ int rows[N_];
    __shared__ float red[256];
    float gm = gmax[0];
    float local = 0.f;
    for (int v = threadIdx.x; v < N_; v += 256) {
        int node = b * N_ + v;
        float wv = expf(e[node] - gm);
        w[v] = wv;
        rows[v] = xidx ? xidx[node] : node;
        local += wv;
    }
    red[threadIdx.x] = local;
    __syncthreads();
    for (int s = 128; s > 0; s >>= 1) {
        if (threadIdx.x < (unsigned)s) red[threadIdx.x] += red[threadIdx.x + s];
        __syncthreads();
    }
    float inv = 1.0f / (red[0] + 1e-10f);
    for (int d = threadIdx.x; d < dim; d += 256) {
        float acc = 0.f, mx = -3.4e38f;
        for (int v = 0; v < N_; ++v) {
            float xx = h[(size_t)rows[v] * stride + d];
            acc += w[v] * xx;
            mx = fmaxf(mx, xx);
        }
        p[(size_t)b * 2 * dim + d] = acc * inv;
        p[(size_t)b * 2 * dim + dim + d] = mx;
    }
}

// ---------------- final prediction ---------------------------------------------------
__global__ __launch_bounds__(64) void final_kernel(const float* p0, const float* p1, const float* p2,
                                                   const float* pW0, const float* pb0,
                                                   const float* pW1, const float* pb1,
                                                   const float* pW2, const float* pb2, float* out) {
    int b = blockIdx.x;
    int c = threadIdx.x;
    if (c >= NC_) return;
    float s = pb0[c] + pb1[c] + pb2[c];
    for (int k = 0; k < 2 * D_; ++k) s += p0[(size_t)b * 2 * D_ + k] * pW0[k * NC_ + c];
    for (int k = 0; k < 2 * HID_; ++k) s += p1[(size_t)b * 2 * HID_ + k] * pW1[k * NC_ + c];
    for (int k = 0; k < 2 * HID_; ++k) s += p2[(size_t)b * 2 * HID_ + k] * pW2[k * NC_ + c];
    out[b * NC_ + c] = s;
}

extern "C" void kernel_launch(void* const* d_in, const int* in_sizes, int n_in,
                              void* d_out, int out_size, void* d_ws, size_t ws_size,
                              hipStream_t stream) {
    const int*   x         = (const int*)d_in[0];
    const int*   inc_rows  = (const int*)d_in[1];
    const int*   inc_cols  = (const int*)d_in[2];
    const float* inc_vals  = (const float*)d_in[3];
    const int*   sent_rows = (const int*)d_in[4];
    const int*   sent_cols = (const int*)d_in[5];
    const float* sent_vals = (const float*)d_in[6];
    const float* deg_v     = (const float*)d_in[7];
    const float* deg_e     = (const float*)d_in[8];
    const float* tf_idf = (const float*)d_in[11];
    const float* emb    = (const float*)d_in[12];
    const float* W1 = (const float*)d_in[13];
    const float* b1 = (const float*)d_in[14];
    const float* W2 = (const float*)d_in[15];
    const float* b2 = (const float*)d_in[16];
    const float* attW0 = (const float*)d_in[17];
    const float* attb0 = (const float*)d_in[18];
    const float* attW1 = (const float*)d_in[19];
    const float* attb1 = (const float*)d_in[20];
    const float* attW2 = (const float*)d_in[21];
    const float* attb2 = (const float*)d_in[22];
    const float* pW0 = (const float*)d_in[23];
    const float* pb0 = (const float*)d_in[24];
    const float* pW1 = (const float*)d_in[25];
    const float* pb1 = (const float*)d_in[26];
    const float* pW2 = (const float*)d_in[27];
    const float* pb2 = (const float*)d_in[28];
    float* out = (float*)d_out;

    // workspace layout
    char* ws = (char*)d_ws;
    size_t off = 0;
    auto alloc = [&](size_t bytes) {
        void* p = ws + off;
        off += (bytes + 255) & ~(size_t)255;
        return p;
    };
    float* hv = (float*)alloc((size_t)NV_ * 304 * sizeof(float)); // padded stride for K=300
    float* m  = (float*)alloc((size_t)NE_ * D_ * sizeof(float));
    float* m2 = (float*)alloc((size_t)NE_ * D_ * sizeof(float));
    float* h1 = (float*)alloc((size_t)NV_ * HID_ * sizeof(float));
    float* h2 = (float*)alloc((size_t)NV_ * HID_ * sizeof(float));
    float* e  = (float*)alloc((size_t)NV_ * sizeof(float));
    float* gmax = (float*)alloc(256);
    float* p0 = (float*)alloc((size_t)B_ * 2 * D_ * sizeof(float));
    float* p1 = (float*)alloc((size_t)B_ * 2 * HID_ * sizeof(float));
    float* p2 = (float*)alloc((size_t)B_ * 2 * HID_ * sizeof(float));
    // CSR structures (built once per call, reused by both layers)
    int* cnt      = (int*)alloc((size_t)(NE_ + NV_ + NE_) * sizeof(int)); // e, v, s counters
    int* cnt_e = cnt;
    int* cnt_v = cnt + NE_;
    int* cnt_s = cnt + NE_ + NV_;
    int* rowptr_e = (int*)alloc((size_t)(NE_ + 1) * sizeof(int));
    int* rowptr_v = (int*)alloc((size_t)(NV_ + 1) * sizeof(int));
    int* rowptr_s = (int*)alloc((size_t)(NE_ + 1) * sizeof(int));
    int* fill_e   = (int*)alloc((size_t)NE_ * sizeof(int));
    int* fill_v   = (int*)alloc((size_t)NV_ * sizeof(int));
    int* fill_s   = (int*)alloc((size_t)NE_ * sizeof(int));
    int*   srcA_e = (int*)  alloc((size_t)NNZ_ * sizeof(int));
    float* val_e  = (float*)alloc((size_t)NNZ_ * sizeof(float));
    int*   srcA_v = (int*)  alloc((size_t)NNZ_ * sizeof(int));
    float* val_v  = (float*)alloc((size_t)NNZ_ * sizeof(float));
    int*   srcA_s = (int*)  alloc((size_t)SNNZ_ * sizeof(int));
    float* val_s  = (float*)alloc((size_t)SNNZ_ * sizeof(float));

    // ---- build CSR (segment lists) for inc-by-col, inc-by-row, sent-by-col ----
    hipMemsetAsync(cnt, 0, (size_t)(NE_ + NV_ + NE_) * sizeof(int), stream);
    hist_kernel<<<NNZ_ / 256, 256, 0, stream>>>(inc_cols, NNZ_, cnt_e);
    hist_kernel<<<NNZ_ / 256, 256, 0, stream>>>(inc_rows, NNZ_, cnt_v);
    hist_kernel<<<SNNZ_ / 256, 256, 0, stream>>>(sent_cols, SNNZ_, cnt_s);
    scan_kernel<<<1, 1024, 0, stream>>>(cnt_e, NE_, rowptr_e, fill_e);
    scan_kernel<<<1, 1024, 0, stream>>>(cnt_v, NV_, rowptr_v, fill_v);
    scan_kernel<<<1, 1024, 0, stream>>>(cnt_s, NE_, rowptr_s, fill_s);
    place_kernel<<<NNZ_ / 256, 256, 0, stream>>>(inc_cols, inc_rows, inc_vals, NNZ_,
                                                 fill_e, srcA_e, val_e);
    place_kernel<<<NNZ_ / 256, 256, 0, stream>>>(inc_rows, inc_cols, inc_vals, NNZ_,
                                                 fill_v, srcA_v, val_v);
    place_kernel<<<SNNZ_ / 256, 256, 0, stream>>>(sent_cols, sent_rows, sent_vals, SNNZ_,
                                                  fill_s, srcA_s, val_s);

    // ---- layer 1 (input = emb[x], dim 300) ----
    gather_kernel<D_><<<NE_ / 4, 256, 0, stream>>>(rowptr_e, srcA_e, val_e, x,
                                                   emb, D_, deg_e, m, D_, NE_);
    gather_kernel<D_><<<NE_ / 4, 256, 0, stream>>>(rowptr_s, srcA_s, val_s, nullptr,
                                                   m, D_, nullptr, m2, D_, NE_);
    gather_kernel<D_><<<NV_ / 4, 256, 0, stream>>>(rowptr_v, srcA_v, val_v, nullptr,
                                                   m2, D_, nullptr, hv, 304, NV_);
    {
        dim3 grid(NV_ / 64, HID_ / 64);
        gemm_relu_kernel<<<grid, 256, 0, stream>>>(hv, 304, D_, W1, b1, deg_v, h1);
    }

    // ---- layer 2 (input = h1, dim 256) ----
    gather_kernel<HID_><<<NE_ / 4, 256, 0, stream>>>(rowptr_e, srcA_e, val_e, nullptr,
                                                     h1, HID_, deg_e, m, HID_, NE_);
    gather_kernel<HID_><<<NE_ / 4, 256, 0, stream>>>(rowptr_s, srcA_s, val_s, nullptr,
                                                     m, HID_, nullptr, m2, HID_, NE_);
    gather_kernel<HID_><<<NV_ / 4, 256, 0, stream>>>(rowptr_v, srcA_v, val_v, nullptr,
                                                     m2, HID_, nullptr, hv, HID_, NV_);
    {
        dim3 grid(NV_ / 64, HID_ / 64);
        gemm_relu_kernel<<<grid, 256, 0, stream>>>(hv, HID_, HID_, W2, b2, deg_v, h2);
    }

    // ---- pools ----
    logits_kernel<<<NV_ / 4, 256, 0, stream>>>(emb, D_, D_, x, tf_idf, attW0, attb0, e);
    gmax_kernel<<<1, 1024, 0, stream>>>(e, gmax);
    pool_kernel<<<B_, 256, 0, stream>>>(emb, D_, D_, x, e, gmax, p0);

    logits_kernel<<<NV_ / 4, 256, 0, stream>>>(h1, HID_, HID_, nullptr, tf_idf, attW1, attb1, e);
    gmax_kernel<<<1, 1024, 0, stream>>>(e, gmax);
    pool_kernel<<<B_, 256, 0, stream>>>(h1, HID_, HID_, nullptr, e, gmax, p1);

    logits_kernel<<<NV_ / 4, 256, 0, stream>>>(h2, HID_, HID_, nullptr, tf_idf, attW2, attb2, e);
    gmax_kernel<<<1, 1024, 0, stream>>>(e, gmax);
    pool_kernel<<<B_, 256, 0, stream>>>(h2, HID_, HID_, nullptr, e, gmax, p2);

    // ---- final linear ----
    final_kernel<<<B_, 64, 0, stream>>>(p0, p1, p2, pW0, pb0, pW1, pb1, pW2, pb2, out);
}

// Round 4
// 681.859 us; speedup vs baseline: 2.1742x; 1.1944x over previous
//
#include <hip/hip_runtime.h>
#include <cstddef>

#define B_   64
#define N_   512
#define NV_  32768
#define NE_  8192
#define NNZ_ 262144
#define SNNZ_ 24576
#define D_   300
#define HID_ 256
#define NC_  10
#define PCHUNK 8
#define PVN (N_ / PCHUNK)   // 64 nodes per pool chunk

// ---------------- CSR build: histogram -> exclusive scan -> placement ---------------
__global__ __launch_bounds__(256) void hist_kernel(const int* __restrict__ keys, int n,
                                                   int* __restrict__ cnt) {
    int i = blockIdx.x * 256 + threadIdx.x;
    if (i < n) atomicAdd(&cnt[keys[i]], 1);
}

// single block, n multiple of 1024
__global__ __launch_bounds__(1024) void scan_kernel(const int* __restrict__ cnt, int n,
                                                    int* __restrict__ rowptr,
                                                    int* __restrict__ fill) {
    __shared__ int part[1024];
    int t = threadIdx.x;
    int per = n / 1024;
    int base = t * per;
    int s = 0;
    for (int i = 0; i < per; ++i) s += cnt[base + i];
    part[t] = s;
    __syncthreads();
    for (int off = 1; off < 1024; off <<= 1) {
        int add = (t >= off) ? part[t - off] : 0;
        __syncthreads();
        part[t] += add;
        __syncthreads();
    }
    int run = (t > 0) ? part[t - 1] : 0;
    for (int i = 0; i < per; ++i) {
        rowptr[base + i] = run;
        fill[base + i] = run;
        run += cnt[base + i];
    }
    if (t == 1023) rowptr[n] = run;
}

__global__ __launch_bounds__(256) void place_kernel(const int* __restrict__ keys,
                                                    const int* __restrict__ other,
                                                    const float* __restrict__ vals, int n,
                                                    int* __restrict__ fill,
                                                    int* __restrict__ osrc,
                                                    float* __restrict__ oval) {
    int i = blockIdx.x * 256 + threadIdx.x;
    if (i >= n) return;
    int k = keys[i];
    int p = atomicAdd(&fill[k], 1);
    osrc[p] = other[i];
    oval[p] = vals[i];
}

// ---------------- segment gather-sum (one wave per segment, float4 loads) -----------
// dst[seg][0:DIM] = (gscale?gscale[seg]:1) * sum_k vals[k] * src[row(srcidx[k])][0:DIM]
template <int DIM>
__global__ __launch_bounds__(256) void gather_kernel(const int* __restrict__ rowptr,
                                                     const int* __restrict__ srcidx,
                                                     const float* __restrict__ svals,
                                                     const int* __restrict__ xidx,
                                                     const float* __restrict__ src, int sstride,
                                                     const float* __restrict__ gscale,
                                                     float* __restrict__ dst, int dstride,
                                                     int nseg) {
    int seg = (blockIdx.x * 256 + threadIdx.x) >> 6;
    int lane = threadIdx.x & 63;
    if (seg >= nseg) return;
    int start = rowptr[seg], end = rowptr[seg + 1];
    constexpr int NQ = DIM / 4;               // float4s per row (DIM % 4 == 0)
    constexpr int NF4 = (NQ + 63) / 64;       // float4 accumulators per lane
    float4 acc[NF4];
#pragma unroll
    for (int i = 0; i < NF4; ++i) acc[i] = make_float4(0.f, 0.f, 0.f, 0.f);
    for (int k = start; k < end; ++k) {
        int r = srcidx[k];
        if (xidx) r = xidx[r];
        float v = svals[k];
        const float4* srow = reinterpret_cast<const float4*>(src + (size_t)r * sstride);
#pragma unroll
        for (int i = 0; i < NF4; ++i) {
            int d4 = i * 64 + lane;
            if (NQ % 64 == 0 || d4 < NQ) {
                float4 sv = srow[d4];
                acc[i].x += v * sv.x; acc[i].y += v * sv.y;
                acc[i].z += v * sv.z; acc[i].w += v * sv.w;
            }
        }
    }
    float sc = gscale ? gscale[seg] : 1.f;
    float4* drow = reinterpret_cast<float4*>(dst + (size_t)seg * dstride);
#pragma unroll
    for (int i = 0; i < NF4; ++i) {
        int d4 = i * 64 + lane;
        if (NQ % 64 == 0 || d4 < NQ) {
            float4 o; o.x = sc * acc[i].x; o.y = sc * acc[i].y;
            o.z = sc * acc[i].z; o.w = sc * acc[i].w;
            drow[d4] = o;
        }
    }
}

// ---------------- f32 tiled GEMM + deg scale + bias + relu -------------------------
// C[v][j] = relu(degv[v] * sum_k A[v][k]*W[k][j] + bias[j]),  W row-major [K][256]
__global__ __launch_bounds__(256) void gemm_relu_kernel(const float* A, int lda, int K,
                                                        const float* W, const float* bias,
                                                        const float* degv, float* C) {
    __shared__ float As[16][64];
    __shared__ float Ws[16][68];
    int bm0 = blockIdx.x * 64;
    int bn0 = blockIdx.y * 64;
    int tid = threadIdx.x;
    int tx = tid & 15, ty = tid >> 4;
    int amr = tid >> 2, akc = (tid & 3) * 4;
    int wkr = tid >> 4, wnc = (tid & 15) * 4;
    float acc[4][4] = {};
    int ktiles = (K + 15) / 16;
    const float* Arow = A + (size_t)(bm0 + amr) * lda + akc;
    for (int kt = 0; kt < ktiles; ++kt) {
        int k0 = kt * 16;
        float4 av = *reinterpret_cast<const float4*>(Arow + k0);
        As[akc + 0][amr] = av.x;
        As[akc + 1][amr] = av.y;
        As[akc + 2][amr] = av.z;
        As[akc + 3][amr] = av.w;
        int krow = k0 + wkr;
        float4 wv = make_float4(0.f, 0.f, 0.f, 0.f);
        if (krow < K)
            wv = *reinterpret_cast<const float4*>(W + (size_t)krow * HID_ + bn0 + wnc);
        Ws[wkr][wnc + 0] = wv.x; Ws[wkr][wnc + 1] = wv.y;
        Ws[wkr][wnc + 2] = wv.z; Ws[wkr][wnc + 3] = wv.w;
        __syncthreads();
#pragma unroll
        for (int k = 0; k < 16; ++k) {
            float4 a = *reinterpret_cast<const float4*>(&As[k][ty * 4]);
            float4 w = *reinterpret_cast<const float4*>(&Ws[k][tx * 4]);
            acc[0][0] += a.x * w.x; acc[0][1] += a.x * w.y; acc[0][2] += a.x * w.z; acc[0][3] += a.x * w.w;
            acc[1][0] += a.y * w.x; acc[1][1] += a.y * w.y; acc[1][2] += a.y * w.z; acc[1][3] += a.y * w.w;
            acc[2][0] += a.z * w.x; acc[2][1] += a.z * w.y; acc[2][2] += a.z * w.z; acc[2][3] += a.z * w.w;
            acc[3][0] += a.w * w.x; acc[3][1] += a.w * w.y; acc[3][2] += a.w * w.z; acc[3][3] += a.w * w.w;
        }
        __syncthreads();
    }
#pragma unroll
    for (int i = 0; i < 4; ++i) {
        int row = bm0 + ty * 4 + i;
        float dv = degv[row];
#pragma unroll
        for (int j = 0; j < 4; ++j) {
            int col = bn0 + tx * 4 + j;
            float v = acc[i][j] * dv + bias[col];
            C[(size_t)row * HID_ + col] = v > 0.f ? v : 0.f;
        }
    }
}

// ---------------- attention logits (float4 dot) --------------------------------------
__global__ __launch_bounds__(256) void logits_kernel(const float* __restrict__ h, int dim,
                                                     int stride, const int* __restrict__ xidx,
                                                     const float* __restrict__ tfidf,
                                                     const float* __restrict__ attW,
                                                     const float* __restrict__ attb,
                                                     float* __restrict__ e) {
    int w = (blockIdx.x * 256 + threadIdx.x) >> 6;
    int lane = threadIdx.x & 63;
    if (w >= NV_) return;
    int row = xidx ? xidx[w] : w;
    const float4* hp = reinterpret_cast<const float4*>(h + (size_t)row * stride);
    const float4* aw = reinterpret_cast<const float4*>(attW);
    int nq = dim >> 2;
    float s = 0.f;
    for (int d4 = lane; d4 < nq; d4 += 64) {
        float4 a = hp[d4], b = aw[d4];
        s += a.x * b.x + a.y * b.y + a.z * b.z + a.w * b.w;
    }
#pragma unroll
    for (int off = 32; off > 0; off >>= 1) s += __shfl_down(s, off);
    if (lane == 0) {
        s += tfidf[w * 2] * attW[dim] + tfidf[w * 2 + 1] * attW[dim + 1] + attb[0];
        e[w] = s;
    }
}

// ---------------- global max of e ---------------------------------------------------
__global__ __launch_bounds__(1024) void gmax_kernel(const float* __restrict__ e,
                                                    float* __restrict__ gmax) {
    __shared__ float red[1024];
    float m = -3.4e38f;
    for (int i = threadIdx.x; i < NV_; i += 1024) m = fmaxf(m, e[i]);
    red[threadIdx.x] = m;
    __syncthreads();
    for (int s = 512; s > 0; s >>= 1) {
        if (threadIdx.x < (unsigned)s) red[threadIdx.x] = fmaxf(red[threadIdx.x], red[threadIdx.x + s]);
        __syncthreads();
    }
    if (threadIdx.x == 0) gmax[0] = red[0];
}

// ---------------- pool stage A: normalized softmax weights per node -----------------
__global__ __launch_bounds__(512) void weights_kernel(const float* __restrict__ e,
                                                      const float* __restrict__ gmax,
                                                      float* __restrict__ w) {
    int b = blockIdx.x;
    int t = threadIdx.x;
    int node = b * N_ + t;
    float wv = expf(e[node] - gmax[0]);
    __shared__ float red[512];
    red[t] = wv;
    __syncthreads();
    for (int s = 256; s > 0; s >>= 1) {
        if (t < s) red[t] += red[t + s];
        __syncthreads();
    }
    float inv = 1.f / (red[0] + 1e-10f);
    w[node] = wv * inv;
}

// ---------------- pool stage B: partial weighted-sum + max over 64-node chunks ------
__global__ __launch_bounds__(256) void pool_partial_kernel(const float* __restrict__ h, int dim,
                                                           int stride, const int* __restrict__ xidx,
                                                           const float* __restrict__ w,
                                                           float* __restrict__ psum,
                                                           float* __restrict__ pmax) {
    int b = blockIdx.x, c = blockIdx.y;
    __shared__ int rows[PVN];
    __shared__ float wv[PVN];
    int t = threadIdx.x;
    if (t < PVN) {
        int node = b * N_ + c * PVN + t;
        rows[t] = xidx ? xidx[node] : node;
        wv[t] = w[node];
    }
    __syncthreads();
    float s0 = 0.f, s1 = 0.f, m0 = -3.4e38f, m1 = -3.4e38f;
    int d0 = t, d1 = t + 256;
    bool has1 = d1 < dim;
    for (int i = 0; i < PVN; ++i) {
        const float* hp = h + (size_t)rows[i] * stride;
        float ww = wv[i];
        float x0 = hp[d0];
        s0 += ww * x0;
        m0 = fmaxf(m0, x0);
        if (has1) {
            float x1 = hp[d1];
            s1 += ww * x1;
            m1 = fmaxf(m1, x1);
        }
    }
    size_t base = ((size_t)b * PCHUNK + c) * dim;
    psum[base + d0] = s0;
    pmax[base + d0] = m0;
    if (has1) {
        psum[base + d1] = s1;
        pmax[base + d1] = m1;
    }
}

// ---------------- pool stage C: combine chunk partials -------------------------------
__global__ __launch_bounds__(256) void pool_combine_kernel(const float* __restrict__ psum,
                                                           const float* __restrict__ pmax,
                                                           int dim, float* __restrict__ p) {
    int b = blockIdx.x;
    for (int d = threadIdx.x; d < dim; d += 256) {
        float s = 0.f, m = -3.4e38f;
        for (int c = 0; c < PCHUNK; ++c) {
            size_t base = ((size_t)b * PCHUNK + c) * dim;
            s += psum[base + d];
            m = fmaxf(m, pmax[base + d]);
        }
        p[(size_t)b * 2 * dim + d] = s;
        p[(size_t)b * 2 * dim + dim + d] = m;
    }
}

// ---------------- final prediction ---------------------------------------------------
__global__ __launch_bounds__(64) void final_kernel(const float* p0, const float* p1, const float* p2,
                                                   const float* pW0, const float* pb0,
                                                   const float* pW1, const float* pb1,
                                                   const float* pW2, const float* pb2, float* out) {
    int b = blockIdx.x;
    int c = threadIdx.x;
    if (c >= NC_) return;
    float s = pb0[c] + pb1[c] + pb2[c];
    for (int k = 0; k < 2 * D_; ++k) s += p0[(size_t)b * 2 * D_ + k] * pW0[k * NC_ + c];
    for (int k = 0; k < 2 * HID_; ++k) s += p1[(size_t)b * 2 * HID_ + k] * pW1[k * NC_ + c];
    for (int k = 0; k < 2 * HID_; ++k) s += p2[(size_t)b * 2 * HID_ + k] * pW2[k * NC_ + c];
    out[b * NC_ + c] = s;
}

extern "C" void kernel_launch(void* const* d_in, const int* in_sizes, int n_in,
                              void* d_out, int out_size, void* d_ws, size_t ws_size,
                              hipStream_t stream) {
    const int*   x         = (const int*)d_in[0];
    const int*   inc_rows  = (const int*)d_in[1];
    const int*   inc_cols  = (const int*)d_in[2];
    const float* inc_vals  = (const float*)d_in[3];
    const int*   sent_rows = (const int*)d_in[4];
    const int*   sent_cols = (const int*)d_in[5];
    const float* sent_vals = (const float*)d_in[6];
    const float* deg_v     = (const float*)d_in[7];
    const float* deg_e     = (const float*)d_in[8];
    const float* tf_idf = (const float*)d_in[11];
    const float* emb    = (const float*)d_in[12];
    const float* W1 = (const float*)d_in[13];
    const float* b1 = (const float*)d_in[14];
    const float* W2 = (const float*)d_in[15];
    const float* b2 = (const float*)d_in[16];
    const float* attW0 = (const float*)d_in[17];
    const float* attb0 = (const float*)d_in[18];
    const float* attW1 = (const float*)d_in[19];
    const float* attb1 = (const float*)d_in[20];
    const float* attW2 = (const float*)d_in[21];
    const float* attb2 = (const float*)d_in[22];
    const float* pW0 = (const float*)d_in[23];
    const float* pb0 = (const float*)d_in[24];
    const float* pW1 = (const float*)d_in[25];
    const float* pb1 = (const float*)d_in[26];
    const float* pW2 = (const float*)d_in[27];
    const float* pb2 = (const float*)d_in[28];
    float* out = (float*)d_out;

    // workspace layout
    char* ws = (char*)d_ws;
    size_t off = 0;
    auto alloc = [&](size_t bytes) {
        void* p = ws + off;
        off += (bytes + 255) & ~(size_t)255;
        return p;
    };
    float* hv = (float*)alloc((size_t)NV_ * 304 * sizeof(float)); // padded stride for K=300
    float* m  = (float*)alloc((size_t)NE_ * D_ * sizeof(float));
    float* m2 = (float*)alloc((size_t)NE_ * D_ * sizeof(float));
    float* h1 = (float*)alloc((size_t)NV_ * HID_ * sizeof(float));
    float* h2 = (float*)alloc((size_t)NV_ * HID_ * sizeof(float));
    float* e  = (float*)alloc((size_t)NV_ * sizeof(float));
    float* gmax = (float*)alloc(256);
    float* watt = (float*)alloc((size_t)NV_ * sizeof(float));
    float* psum = (float*)alloc((size_t)B_ * PCHUNK * D_ * sizeof(float));
    float* pmax = (float*)alloc((size_t)B_ * PCHUNK * D_ * sizeof(float));
    float* p0 = (float*)alloc((size_t)B_ * 2 * D_ * sizeof(float));
    float* p1 = (float*)alloc((size_t)B_ * 2 * HID_ * sizeof(float));
    float* p2 = (float*)alloc((size_t)B_ * 2 * HID_ * sizeof(float));
    // CSR structures (built once per call, reused by both layers)
    int* cnt      = (int*)alloc((size_t)(NE_ + NV_ + NE_) * sizeof(int)); // e, v, s counters
    int* cnt_e = cnt;
    int* cnt_v = cnt + NE_;
    int* cnt_s = cnt + NE_ + NV_;
    int* rowptr_e = (int*)alloc((size_t)(NE_ + 1) * sizeof(int));
    int* rowptr_v = (int*)alloc((size_t)(NV_ + 1) * sizeof(int));
    int* rowptr_s = (int*)alloc((size_t)(NE_ + 1) * sizeof(int));
    int* fill_e   = (int*)alloc((size_t)NE_ * sizeof(int));
    int* fill_v   = (int*)alloc((size_t)NV_ * sizeof(int));
    int* fill_s   = (int*)alloc((size_t)NE_ * sizeof(int));
    int*   srcA_e = (int*)  alloc((size_t)NNZ_ * sizeof(int));
    float* val_e  = (float*)alloc((size_t)NNZ_ * sizeof(float));
    int*   srcA_v = (int*)  alloc((size_t)NNZ_ * sizeof(int));
    float* val_v  = (float*)alloc((size_t)NNZ_ * sizeof(float));
    int*   srcA_s = (int*)  alloc((size_t)SNNZ_ * sizeof(int));
    float* val_s  = (float*)alloc((size_t)SNNZ_ * sizeof(float));

    // ---- build CSR (segment lists) for inc-by-col, inc-by-row, sent-by-col ----
    hipMemsetAsync(cnt, 0, (size_t)(NE_ + NV_ + NE_) * sizeof(int), stream);
    hist_kernel<<<NNZ_ / 256, 256, 0, stream>>>(inc_cols, NNZ_, cnt_e);
    hist_kernel<<<NNZ_ / 256, 256, 0, stream>>>(inc_rows, NNZ_, cnt_v);
    hist_kernel<<<SNNZ_ / 256, 256, 0, stream>>>(sent_cols, SNNZ_, cnt_s);
    scan_kernel<<<1, 1024, 0, stream>>>(cnt_e, NE_, rowptr_e, fill_e);
    scan_kernel<<<1, 1024, 0, stream>>>(cnt_v, NV_, rowptr_v, fill_v);
    scan_kernel<<<1, 1024, 0, stream>>>(cnt_s, NE_, rowptr_s, fill_s);
    place_kernel<<<NNZ_ / 256, 256, 0, stream>>>(inc_cols, inc_rows, inc_vals, NNZ_,
                                                 fill_e, srcA_e, val_e);
    place_kernel<<<NNZ_ / 256, 256, 0, stream>>>(inc_rows, inc_cols, inc_vals, NNZ_,
                                                 fill_v, srcA_v, val_v);
    place_kernel<<<SNNZ_ / 256, 256, 0, stream>>>(sent_cols, sent_rows, sent_vals, SNNZ_,
                                                  fill_s, srcA_s, val_s);

    // ---- layer 1 (input = emb[x], dim 300) ----
    gather_kernel<D_><<<NE_ / 4, 256, 0, stream>>>(rowptr_e, srcA_e, val_e, x,
                                                   emb, D_, deg_e, m, D_, NE_);
    gather_kernel<D_><<<NE_ / 4, 256, 0, stream>>>(rowptr_s, srcA_s, val_s, nullptr,
                                                   m, D_, nullptr, m2, D_, NE_);
    gather_kernel<D_><<<NV_ / 4, 256, 0, stream>>>(rowptr_v, srcA_v, val_v, nullptr,
                                                   m2, D_, nullptr, hv, 304, NV_);
    {
        dim3 grid(NV_ / 64, HID_ / 64);
        gemm_relu_kernel<<<grid, 256, 0, stream>>>(hv, 304, D_, W1, b1, deg_v, h1);
    }

    // ---- layer 2 (input = h1, dim 256) ----
    gather_kernel<HID_><<<NE_ / 4, 256, 0, stream>>>(rowptr_e, srcA_e, val_e, nullptr,
                                                     h1, HID_, deg_e, m, HID_, NE_);
    gather_kernel<HID_><<<NE_ / 4, 256, 0, stream>>>(rowptr_s, srcA_s, val_s, nullptr,
                                                     m, HID_, nullptr, m2, HID_, NE_);
    gather_kernel<HID_><<<NV_ / 4, 256, 0, stream>>>(rowptr_v, srcA_v, val_v, nullptr,
                                                     m2, HID_, nullptr, hv, HID_, NV_);
    {
        dim3 grid(NV_ / 64, HID_ / 64);
        gemm_relu_kernel<<<grid, 256, 0, stream>>>(hv, HID_, HID_, W2, b2, deg_v, h2);
    }

    // ---- pools ----
    dim3 pgrid(B_, PCHUNK);
    logits_kernel<<<NV_ / 4, 256, 0, stream>>>(emb, D_, D_, x, tf_idf, attW0, attb0, e);
    gmax_kernel<<<1, 1024, 0, stream>>>(e, gmax);
    weights_kernel<<<B_, 512, 0, stream>>>(e, gmax, watt);
    pool_partial_kernel<<<pgrid, 256, 0, stream>>>(emb, D_, D_, x, watt, psum, pmax);
    pool_combine_kernel<<<B_, 256, 0, stream>>>(psum, pmax, D_, p0);

    logits_kernel<<<NV_ / 4, 256, 0, stream>>>(h1, HID_, HID_, nullptr, tf_idf, attW1, attb1, e);
    gmax_kernel<<<1, 1024, 0, stream>>>(e, gmax);
    weights_kernel<<<B_, 512, 0, stream>>>(e, gmax, watt);
    pool_partial_kernel<<<pgrid, 256, 0, stream>>>(h1, HID_, HID_, nullptr, watt, psum, pmax);
    pool_combine_kernel<<<B_, 256, 0, stream>>>(psum, pmax, HID_, p1);

    logits_kernel<<<NV_ / 4, 256, 0, stream>>>(h2, HID_, HID_, nullptr, tf_idf, attW2, attb2, e);
    gmax_kernel<<<1, 1024, 0, stream>>>(e, gmax);
    weights_kernel<<<B_, 512, 0, stream>>>(e, gmax, watt);
    pool_partial_kernel<<<pgrid, 256, 0, stream>>>(h2, HID_, HID_, nullptr, watt, psum, pmax);
    pool_combine_kernel<<<B_, 256, 0, stream>>>(psum, pmax, HID_, p2);

    // ---- final linear ----
    final_kernel<<<B_, 64, 0, stream>>>(p0, p1, p2, pW0, pb0, pW1, pb1, pW2, pb2, out);
}

// Round 5
// 575.544 us; speedup vs baseline: 2.5758x; 1.1847x over previous
//
#include <hip/hip_runtime.h>
#include <cstddef>

#define B_   64
#define N_   512
#define NV_  32768
#define NE_  8192
#define NNZ_ 262144
#define SNNZ_ 24576
#define D_   300
#define HID_ 256
#define NC_  10
#define PCHUNK 8
#define PVN (N_ / PCHUNK)   // 64 nodes per pool chunk

using u16 = unsigned short;
typedef __attribute__((ext_vector_type(8))) short short8;
typedef __attribute__((ext_vector_type(4))) float f32x4;

__device__ __forceinline__ float bf2f(u16 v) {
    union { unsigned int u; float f; } uf;
    uf.u = ((unsigned int)v) << 16;
    return uf.f;
}
__device__ __forceinline__ u16 f2bf(float f) {
    union { float f; unsigned int u; } uf; uf.f = f;
    unsigned int u = uf.u;
    unsigned int r = u + 0x7fffu + ((u >> 16) & 1u);
    return (u16)(r >> 16);
}

// ---------------- CSR build: histogram -> exclusive scan -> placement ---------------
__global__ __launch_bounds__(256) void hist_kernel(const int* __restrict__ keys, int n,
                                                   int* __restrict__ cnt) {
    int i = blockIdx.x * 256 + threadIdx.x;
    if (i < n) atomicAdd(&cnt[keys[i]], 1);
}

// single block, n multiple of 1024
__global__ __launch_bounds__(1024) void scan_kernel(const int* __restrict__ cnt, int n,
                                                    int* __restrict__ rowptr,
                                                    int* __restrict__ fill) {
    __shared__ int part[1024];
    int t = threadIdx.x;
    int per = n / 1024;
    int base = t * per;
    int s = 0;
    for (int i = 0; i < per; ++i) s += cnt[base + i];
    part[t] = s;
    __syncthreads();
    for (int off = 1; off < 1024; off <<= 1) {
        int add = (t >= off) ? part[t - off] : 0;
        __syncthreads();
        part[t] += add;
        __syncthreads();
    }
    int run = (t > 0) ? part[t - 1] : 0;
    for (int i = 0; i < per; ++i) {
        rowptr[base + i] = run;
        fill[base + i] = run;
        run += cnt[base + i];
    }
    if (t == 1023) rowptr[n] = run;
}

__global__ __launch_bounds__(256) void place_kernel(const int* __restrict__ keys,
                                                    const int* __restrict__ other,
                                                    const float* __restrict__ vals, int n,
                                                    int* __restrict__ fill,
                                                    int* __restrict__ osrc,
                                                    float* __restrict__ oval,
                                                    const int* __restrict__ xmap,
                                                    int* __restrict__ osrc2) {
    int i = blockIdx.x * 256 + threadIdx.x;
    if (i >= n) return;
    int k = keys[i];
    int o = other[i];
    int p = atomicAdd(&fill[k], 1);
    osrc[p] = o;
    oval[p] = vals[i];
    if (osrc2) osrc2[p] = xmap[o];
}

// ---------------- 256-dim segment gather-sum (one wave per segment) -----------------
// dst[seg][:] = gscale[seg] * sum_k vals[k]*src[srcidx[k]][:]   (+bias,relu if EPI)
template <bool EPI>
__global__ __launch_bounds__(256) void gather256_kernel(const int* __restrict__ rowptr,
                                                        const int* __restrict__ srcidx,
                                                        const float* __restrict__ svals,
                                                        const float* __restrict__ src,
                                                        const float* __restrict__ gscale,
                                                        const float* __restrict__ bias,
                                                        float* __restrict__ dst, int nseg) {
    int seg = (blockIdx.x * 256 + threadIdx.x) >> 6;
    int lane = threadIdx.x & 63;
    if (seg >= nseg) return;
    int start = rowptr[seg], end = rowptr[seg + 1];
    const float4* src4 = reinterpret_cast<const float4*>(src);
    float4 acc = make_float4(0.f, 0.f, 0.f, 0.f);
    for (int k = start; k < end; ++k) {
        int r = srcidx[k];
        float v = svals[k];
        float4 sv = src4[(size_t)r * 64 + lane];
        acc.x += v * sv.x; acc.y += v * sv.y;
        acc.z += v * sv.z; acc.w += v * sv.w;
    }
    float sc = gscale ? gscale[seg] : 1.f;
    float4 o;
    o.x = sc * acc.x; o.y = sc * acc.y; o.z = sc * acc.z; o.w = sc * acc.w;
    if (EPI) {
        float4 bv = reinterpret_cast<const float4*>(bias)[lane];
        o.x = fmaxf(o.x + bv.x, 0.f); o.y = fmaxf(o.y + bv.y, 0.f);
        o.z = fmaxf(o.z + bv.z, 0.f); o.w = fmaxf(o.w + bv.w, 0.f);
    }
    reinterpret_cast<float4*>(dst)[(size_t)seg * 64 + lane] = o;
}

// ---------------- W -> transposed hi/lo bf16 split ----------------------------------
// Wt[n][k] (n-major, k padded to KP with zeros), from W [K][256] f32
__global__ __launch_bounds__(256) void wconv_kernel(const float* __restrict__ W, int K, int KP,
                                                    u16* __restrict__ Wth, u16* __restrict__ Wtl) {
    int idx = blockIdx.x * 256 + threadIdx.x;
    if (idx >= 256 * KP) return;
    int n = idx & 255;
    int k = idx >> 8;
    float v = (k < K) ? W[(size_t)k * HID_ + n] : 0.f;
    u16 hi = f2bf(v);
    u16 lo = f2bf(v - bf2f(hi));
    Wth[(size_t)n * KP + k] = hi;
    Wtl[(size_t)n * KP + k] = lo;
}

// ---------------- split-bf16 MFMA GEMM: C[M][256] = A[M][K] @ Wt^T ------------------
// A f32 (row stride Ks), Wt hi/lo bf16 [256][bstride]. EPI: C=relu(degv*acc+bias).
template <bool EPI>
__global__ __launch_bounds__(256) void gemm_mfma_kernel(const float* __restrict__ A, int M,
                                                        int K, int Ks,
                                                        const u16* __restrict__ Bth,
                                                        const u16* __restrict__ Btl, int bstride,
                                                        const float* __restrict__ bias,
                                                        const float* __restrict__ degv,
                                                        float* __restrict__ C) {
    __shared__ __align__(16) u16 Ah[64 * 32];
    __shared__ __align__(16) u16 Al[64 * 32];
    __shared__ __align__(16) u16 Bh[64 * 32];
    __shared__ __align__(16) u16 Bl[64 * 32];
    int tid = threadIdx.x;
    int bm0 = blockIdx.x * 64, bn0 = blockIdx.y * 64;
    int w = tid >> 6, l = tid & 63;
    // staging coords: one 8-elem k-chunk per thread per buffer
    int srow = tid >> 2;                 // 0..63
    int skbp = tid & 3;                  // physical k-chunk in LDS
    int skbl = skbp ^ ((srow >> 1) & 3); // logical k-chunk in global (XOR swizzle)
    int arow = bm0 + srow; if (arow >= M) arow = M - 1;
    const float* Arow = A + (size_t)arow * Ks;
    const u16* Bhrow = Bth + (size_t)(bn0 + srow) * bstride;
    const u16* Blrow = Btl + (size_t)(bn0 + srow) * bstride;
    int sdst = srow * 32 + skbp * 8;
    // fragment coords
    int frow = w * 16 + (l & 15);
    int akbp = (l >> 4) ^ ((frow >> 1) & 3);
    const short8* afh = (const short8*)&Ah[frow * 32 + akbp * 8];
    const short8* afl = (const short8*)&Al[frow * 32 + akbp * 8];

    f32x4 acc[4] = {};
    int nkt = (K + 31) / 32;
    for (int kt = 0; kt < nkt; ++kt) {
        if (kt) __syncthreads();
        int kbase = kt * 32 + skbl * 8;
        float av[8];
        if (kbase + 8 <= K) {
            float4 v0 = *reinterpret_cast<const float4*>(Arow + kbase);
            float4 v1 = *reinterpret_cast<const float4*>(Arow + kbase + 4);
            av[0] = v0.x; av[1] = v0.y; av[2] = v0.z; av[3] = v0.w;
            av[4] = v1.x; av[5] = v1.y; av[6] = v1.z; av[7] = v1.w;
        } else {
#pragma unroll
            for (int e = 0; e < 8; ++e) {
                int kk = kbase + e;
                av[e] = (kk < K) ? Arow[kk] : 0.f;
            }
        }
        short8 h8, l8;
#pragma unroll
        for (int e = 0; e < 8; ++e) {
            u16 hi = f2bf(av[e]);
            h8[e] = (short)hi;
            l8[e] = (short)f2bf(av[e] - bf2f(hi));
        }
        *(short8*)&Ah[sdst] = h8;
        *(short8*)&Al[sdst] = l8;
        *(short8*)&Bh[sdst] = *(const short8*)(Bhrow + kt * 32 + skbl * 8);
        *(short8*)&Bl[sdst] = *(const short8*)(Blrow + kt * 32 + skbl * 8);
        __syncthreads();
        short8 ah = *afh;
        short8 al = *afl;
#pragma unroll
        for (int t = 0; t < 4; ++t) {
            int nrow = t * 16 + (l & 15);
            int bkbp = (l >> 4) ^ ((nrow >> 1) & 3);
            short8 tbh = *(const short8*)&Bh[nrow * 32 + bkbp * 8];
            short8 tbl = *(const short8*)&Bl[nrow * 32 + bkbp * 8];
            acc[t] = __builtin_amdgcn_mfma_f32_16x16x32_bf16(ah, tbh, acc[t], 0, 0, 0);
            acc[t] = __builtin_amdgcn_mfma_f32_16x16x32_bf16(al, tbh, acc[t], 0, 0, 0);
            acc[t] = __builtin_amdgcn_mfma_f32_16x16x32_bf16(ah, tbl, acc[t], 0, 0, 0);
        }
    }
#pragma unroll
    for (int r = 0; r < 4; ++r) {
        int row = bm0 + w * 16 + (l >> 4) * 4 + r;
        if (row >= M) continue;
        float dv = EPI ? degv[row] : 0.f;
#pragma unroll
        for (int t = 0; t < 4; ++t) {
            int col = bn0 + t * 16 + (l & 15);
            float v = acc[t][r];
            if (EPI) {
                v = v * dv + bias[col];
                v = v > 0.f ? v : 0.f;
            }
            C[(size_t)row * HID_ + col] = v;
        }
    }
}

// ---------------- attention logits (float4 dot) --------------------------------------
__global__ __launch_bounds__(256) void logits_kernel(const float* __restrict__ h, int dim,
                                                     int stride, const int* __restrict__ xidx,
                                                     const float* __restrict__ tfidf,
                                                     const float* __restrict__ attW,
                                                     const float* __restrict__ attb,
                                                     float* __restrict__ e) {
    int w = (blockIdx.x * 256 + threadIdx.x) >> 6;
    int lane = threadIdx.x & 63;
    if (w >= NV_) return;
    int row = xidx ? xidx[w] : w;
    const float4* hp = reinterpret_cast<const float4*>(h + (size_t)row * stride);
    const float4* aw = reinterpret_cast<const float4*>(attW);
    int nq = dim >> 2;
    float s = 0.f;
    for (int d4 = lane; d4 < nq; d4 += 64) {
        float4 a = hp[d4], b = aw[d4];
        s += a.x * b.x + a.y * b.y + a.z * b.z + a.w * b.w;
    }
#pragma unroll
    for (int off = 32; off > 0; off >>= 1) s += __shfl_down(s, off);
    if (lane == 0) {
        s += tfidf[w * 2] * attW[dim] + tfidf[w * 2 + 1] * attW[dim + 1] + attb[0];
        e[w] = s;
    }
}

// ---------------- global max of e ---------------------------------------------------
__global__ __launch_bounds__(1024) void gmax_kernel(const float* __restrict__ e,
                                                    float* __restrict__ gmax) {
    __shared__ float red[1024];
    float m = -3.4e38f;
    for (int i = threadIdx.x; i < NV_; i += 1024) m = fmaxf(m, e[i]);
    red[threadIdx.x] = m;
    __syncthreads();
    for (int s = 512; s > 0; s >>= 1) {
        if (threadIdx.x < (unsigned)s) red[threadIdx.x] = fmaxf(red[threadIdx.x], red[threadIdx.x + s]);
        __syncthreads();
    }
    if (threadIdx.x == 0) gmax[0] = red[0];
}

// ---------------- pool stage A: normalized softmax weights per node -----------------
__global__ __launch_bounds__(512) void weights_kernel(const float* __restrict__ e,
                                                      const float* __restrict__ gmax,
                                                      float* __restrict__ w) {
    int b = blockIdx.x;
    int t = threadIdx.x;
    int node = b * N_ + t;
    float wv = expf(e[node] - gmax[0]);
    __shared__ float red[512];
    red[t] = wv;
    __syncthreads();
    for (int s = 256; s > 0; s >>= 1) {
        if (t < s) red[t] += red[t + s];
        __syncthreads();
    }
    float inv = 1.f / (red[0] + 1e-10f);
    w[node] = wv * inv;
}

// ---------------- pool stage B: partial weighted-sum + max over 64-node chunks ------
__global__ __launch_bounds__(256) void pool_partial_kernel(const float* __restrict__ h, int dim,
                                                           int stride, const int* __restrict__ xidx,
                                                           const float* __restrict__ w,
                                                           float* __restrict__ psum,
                                                           float* __restrict__ pmax) {
    int b = blockIdx.x, c = blockIdx.y;
    __shared__ int rows[PVN];
    __shared__ float wv[PVN];
    int t = threadIdx.x;
    if (t < PVN) {
        int node = b * N_ + c * PVN + t;
        rows[t] = xidx ? xidx[node] : node;
        wv[t] = w[node];
    }
    __syncthreads();
    float s0 = 0.f, s1 = 0.f, m0 = -3.4e38f, m1 = -3.4e38f;
    int d0 = t, d1 = t + 256;
    bool has1 = d1 < dim;
    for (int i = 0; i < PVN; ++i) {
        const float* hp = h + (size_t)rows[i] * stride;
        float ww = wv[i];
        float x0 = hp[d0];
        s0 += ww * x0;
        m0 = fmaxf(m0, x0);
        if (has1) {
            float x1 = hp[d1];
            s1 += ww * x1;
            m1 = fmaxf(m1, x1);
        }
    }
    size_t base = ((size_t)b * PCHUNK + c) * dim;
    psum[base + d0] = s0;
    pmax[base + d0] = m0;
    if (has1) {
        psum[base + d1] = s1;
        pmax[base + d1] = m1;
    }
}

// ---------------- pool stage C: combine chunk partials -------------------------------
__global__ __launch_bounds__(256) void pool_combine_kernel(const float* __restrict__ psum,
                                                           const float* __restrict__ pmax,
                                                           int dim, float* __restrict__ p) {
    int b = blockIdx.x;
    for (int d = threadIdx.x; d < dim; d += 256) {
        float s = 0.f, m = -3.4e38f;
        for (int c = 0; c < PCHUNK; ++c) {
            size_t base = ((size_t)b * PCHUNK + c) * dim;
            s += psum[base + d];
            m = fmaxf(m, pmax[base + d]);
        }
        p[(size_t)b * 2 * dim + d] = s;
        p[(size_t)b * 2 * dim + dim + d] = m;
    }
}

// ---------------- final prediction ---------------------------------------------------
__global__ __launch_bounds__(64) void final_kernel(const float* p0, const float* p1, const float* p2,
                                                   const float* pW0, const float* pb0,
                                                   const float* pW1, const float* pb1,
                                                   const float* pW2, const float* pb2, float* out) {
    int b = blockIdx.x;
    int c = threadIdx.x;
    if (c >= NC_) return;
    float s = pb0[c] + pb1[c] + pb2[c];
    for (int k = 0; k < 2 * D_; ++k) s += p0[(size_t)b * 2 * D_ + k] * pW0[k * NC_ + c];
    for (int k = 0; k < 2 * HID_; ++k) s += p1[(size_t)b * 2 * HID_ + k] * pW1[k * NC_ + c];
    for (int k = 0; k < 2 * HID_; ++k) s += p2[(size_t)b * 2 * HID_ + k] * pW2[k * NC_ + c];
    out[b * NC_ + c] = s;
}

extern "C" void kernel_launch(void* const* d_in, const int* in_sizes, int n_in,
                              void* d_out, int out_size, void* d_ws, size_t ws_size,
                              hipStream_t stream) {
    const int*   x         = (const int*)d_in[0];
    const int*   inc_rows  = (const int*)d_in[1];
    const int*   inc_cols  = (const int*)d_in[2];
    const float* inc_vals  = (const float*)d_in[3];
    const int*   sent_rows = (const int*)d_in[4];
    const int*   sent_cols = (const int*)d_in[5];
    const float* sent_vals = (const float*)d_in[6];
    const float* deg_v     = (const float*)d_in[7];
    const float* deg_e     = (const float*)d_in[8];
    const float* tf_idf = (const float*)d_in[11];
    const float* emb    = (const float*)d_in[12];
    const float* W1 = (const float*)d_in[13];
    const float* b1 = (const float*)d_in[14];
    const float* W2 = (const float*)d_in[15];
    const float* b2 = (const float*)d_in[16];
    const float* attW0 = (const float*)d_in[17];
    const float* attb0 = (const float*)d_in[18];
    const float* attW1 = (const float*)d_in[19];
    const float* attb1 = (const float*)d_in[20];
    const float* attW2 = (const float*)d_in[21];
    const float* attb2 = (const float*)d_in[22];
    const float* pW0 = (const float*)d_in[23];
    const float* pb0 = (const float*)d_in[24];
    const float* pW1 = (const float*)d_in[25];
    const float* pb1 = (const float*)d_in[26];
    const float* pW2 = (const float*)d_in[27];
    const float* pb2 = (const float*)d_in[28];
    float* out = (float*)d_out;

    const int VOCAB = 30000;

    // workspace layout
    char* ws = (char*)d_ws;
    size_t off = 0;
    auto alloc = [&](size_t bytes) {
        void* p = ws + off;
        off += (bytes + 255) & ~(size_t)255;
        return p;
    };
    float* EW = (float*)alloc((size_t)VOCAB * HID_ * sizeof(float)); // emb @ W1
    float* hv = (float*)alloc((size_t)NV_ * HID_ * sizeof(float));
    float* m  = (float*)alloc((size_t)NE_ * HID_ * sizeof(float));
    float* m2 = (float*)alloc((size_t)NE_ * HID_ * sizeof(float));
    float* h1 = (float*)alloc((size_t)NV_ * HID_ * sizeof(float));
    float* h2 = (float*)alloc((size_t)NV_ * HID_ * sizeof(float));
    u16* Wt1h = (u16*)alloc((size_t)HID_ * 320 * sizeof(u16));
    u16* Wt1l = (u16*)alloc((size_t)HID_ * 320 * sizeof(u16));
    u16* Wt2h = (u16*)alloc((size_t)HID_ * 256 * sizeof(u16));
    u16* Wt2l = (u16*)alloc((size_t)HID_ * 256 * sizeof(u16));
    float* e  = (float*)alloc((size_t)NV_ * sizeof(float));
    float* gmax = (float*)alloc(256);
    float* watt = (float*)alloc((size_t)NV_ * sizeof(float));
    float* psum = (float*)alloc((size_t)B_ * PCHUNK * D_ * sizeof(float));
    float* pmax = (float*)alloc((size_t)B_ * PCHUNK * D_ * sizeof(float));
    float* p0 = (float*)alloc((size_t)B_ * 2 * D_ * sizeof(float));
    float* p1 = (float*)alloc((size_t)B_ * 2 * HID_ * sizeof(float));
    float* p2 = (float*)alloc((size_t)B_ * 2 * HID_ * sizeof(float));
    // CSR structures
    int* cnt      = (int*)alloc((size_t)(NE_ + NV_ + NE_) * sizeof(int));
    int* cnt_e = cnt;
    int* cnt_v = cnt + NE_;
    int* cnt_s = cnt + NE_ + NV_;
    int* rowptr_e = (int*)alloc((size_t)(NE_ + 1) * sizeof(int));
    int* rowptr_v = (int*)alloc((size_t)(NV_ + 1) * sizeof(int));
    int* rowptr_s = (int*)alloc((size_t)(NE_ + 1) * sizeof(int));
    int* fill_e   = (int*)alloc((size_t)NE_ * sizeof(int));
    int* fill_v   = (int*)alloc((size_t)NV_ * sizeof(int));
    int* fill_s   = (int*)alloc((size_t)NE_ * sizeof(int));
    int*   srcA_e = (int*)  alloc((size_t)NNZ_ * sizeof(int));  // node ids (layer 2)
    int*   srcX_e = (int*)  alloc((size_t)NNZ_ * sizeof(int));  // x[node] ids (layer 1)
    float* val_e  = (float*)alloc((size_t)NNZ_ * sizeof(float));
    int*   srcA_v = (int*)  alloc((size_t)NNZ_ * sizeof(int));
    float* val_v  = (float*)alloc((size_t)NNZ_ * sizeof(float));
    int*   srcA_s = (int*)  alloc((size_t)SNNZ_ * sizeof(int));
    float* val_s  = (float*)alloc((size_t)SNNZ_ * sizeof(float));

    // ---- build CSR ----
    hipMemsetAsync(cnt, 0, (size_t)(NE_ + NV_ + NE_) * sizeof(int), stream);
    hist_kernel<<<NNZ_ / 256, 256, 0, stream>>>(inc_cols, NNZ_, cnt_e);
    hist_kernel<<<NNZ_ / 256, 256, 0, stream>>>(inc_rows, NNZ_, cnt_v);
    hist_kernel<<<SNNZ_ / 256, 256, 0, stream>>>(sent_cols, SNNZ_, cnt_s);
    scan_kernel<<<1, 1024, 0, stream>>>(cnt_e, NE_, rowptr_e, fill_e);
    scan_kernel<<<1, 1024, 0, stream>>>(cnt_v, NV_, rowptr_v, fill_v);
    scan_kernel<<<1, 1024, 0, stream>>>(cnt_s, NE_, rowptr_s, fill_s);
    place_kernel<<<NNZ_ / 256, 256, 0, stream>>>(inc_cols, inc_rows, inc_vals, NNZ_,
                                                 fill_e, srcA_e, val_e, x, srcX_e);
    place_kernel<<<NNZ_ / 256, 256, 0, stream>>>(inc_rows, inc_cols, inc_vals, NNZ_,
                                                 fill_v, srcA_v, val_v, nullptr, nullptr);
    place_kernel<<<SNNZ_ / 256, 256, 0, stream>>>(sent_cols, sent_rows, sent_vals, SNNZ_,
                                                  fill_s, srcA_s, val_s, nullptr, nullptr);

    // ---- weight conversion (transpose + bf16 hi/lo split) ----
    wconv_kernel<<<(256 * 320 + 255) / 256, 256, 0, stream>>>(W1, D_, 320, Wt1h, Wt1l);
    wconv_kernel<<<(256 * 256 + 255) / 256, 256, 0, stream>>>(W2, HID_, 256, Wt2h, Wt2l);

    // ---- EW = emb @ W1  (vocab-side GEMM; layer-1 linear hoisted before sparse chain)
    {
        dim3 grid((VOCAB + 63) / 64, HID_ / 64);
        gemm_mfma_kernel<false><<<grid, 256, 0, stream>>>(emb, VOCAB, D_, D_,
                                                          Wt1h, Wt1l, 320,
                                                          nullptr, nullptr, EW);
    }

    // ---- layer 1 sparse chain @ dim 256 ----
    gather256_kernel<false><<<NE_ / 4, 256, 0, stream>>>(rowptr_e, srcX_e, val_e,
                                                         EW, deg_e, nullptr, m, NE_);
    gather256_kernel<false><<<NE_ / 4, 256, 0, stream>>>(rowptr_s, srcA_s, val_s,
                                                         m, nullptr, nullptr, m2, NE_);
    gather256_kernel<true><<<NV_ / 4, 256, 0, stream>>>(rowptr_v, srcA_v, val_v,
                                                        m2, deg_v, b1, h1, NV_);

    // ---- layer 2 ----
    gather256_kernel<false><<<NE_ / 4, 256, 0, stream>>>(rowptr_e, srcA_e, val_e,
                                                         h1, deg_e, nullptr, m, NE_);
    gather256_kernel<false><<<NE_ / 4, 256, 0, stream>>>(rowptr_s, srcA_s, val_s,
                                                         m, nullptr, nullptr, m2, NE_);
    gather256_kernel<false><<<NV_ / 4, 256, 0, stream>>>(rowptr_v, srcA_v, val_v,
                                                         m2, nullptr, nullptr, hv, NV_);
    {
        dim3 grid(NV_ / 64, HID_ / 64);
        gemm_mfma_kernel<true><<<grid, 256, 0, stream>>>(hv, NV_, HID_, HID_,
                                                         Wt2h, Wt2l, 256,
                                                         b2, deg_v, h2);
    }

    // ---- pools ----
    dim3 pgrid(B_, PCHUNK);
    logits_kernel<<<NV_ / 4, 256, 0, stream>>>(emb, D_, D_, x, tf_idf, attW0, attb0, e);
    gmax_kernel<<<1, 1024, 0, stream>>>(e, gmax);
    weights_kernel<<<B_, 512, 0, stream>>>(e, gmax, watt);
    pool_partial_kernel<<<pgrid, 256, 0, stream>>>(emb, D_, D_, x, watt, psum, pmax);
    pool_combine_kernel<<<B_, 256, 0, stream>>>(psum, pmax, D_, p0);

    logits_kernel<<<NV_ / 4, 256, 0, stream>>>(h1, HID_, HID_, nullptr, tf_idf, attW1, attb1, e);
    gmax_kernel<<<1, 1024, 0, stream>>>(e, gmax);
    weights_kernel<<<B_, 512, 0, stream>>>(e, gmax, watt);
    pool_partial_kernel<<<pgrid, 256, 0, stream>>>(h1, HID_, HID_, nullptr, watt, psum, pmax);
    pool_combine_kernel<<<B_, 256, 0, stream>>>(psum, pmax, HID_, p1);

    logits_kernel<<<NV_ / 4, 256, 0, stream>>>(h2, HID_, HID_, nullptr, tf_idf, attW2, attb2, e);
    gmax_kernel<<<1, 1024, 0, stream>>>(e, gmax);
    weights_kernel<<<B_, 512, 0, stream>>>(e, gmax, watt);
    pool_partial_kernel<<<pgrid, 256, 0, stream>>>(h2, HID_, HID_, nullptr, watt, psum, pmax);
    pool_combine_kernel<<<B_, 256, 0, stream>>>(psum, pmax, HID_, p2);

    // ---- final linear ----
    final_kernel<<<B_, 64, 0, stream>>>(p0, p1, p2, pW0, pb0, pW1, pb1, pW2, pb2, out);
}

// Round 6
// 497.320 us; speedup vs baseline: 2.9810x; 1.1573x over previous
//
#include <hip/hip_runtime.h>
#include <cstddef>

#define B_   64
#define N_   512
#define NV_  32768
#define NE_  8192
#define NNZ_ 262144
#define SNNZ_ 24576
#define D_   300
#define HID_ 256
#define NC_  10
#define PCHUNK 8
#define PVN (N_ / PCHUNK)   // 64 nodes per pool chunk

#define SCAN_TOT (NE_ + NV_ + NE_)      // 49152 counts, contiguous [cnt_e|cnt_v|cnt_s]
#define SCAN_NCH (SCAN_TOT / 1024)      // 48 chunks
#define SEG1_CH  (NE_ / 1024)           // 8  (start of cnt_v chunks)
#define SEG2_CH  ((NE_ + NV_) / 1024)   // 40 (start of cnt_s chunks)

using u16 = unsigned short;
typedef __attribute__((ext_vector_type(8))) short short8;
typedef __attribute__((ext_vector_type(4))) float f32x4;

__device__ __forceinline__ float bf2f(u16 v) {
    union { unsigned int u; float f; } uf;
    uf.u = ((unsigned int)v) << 16;
    return uf.f;
}
__device__ __forceinline__ u16 f2bf(float f) {
    union { float f; unsigned int u; } uf; uf.f = f;
    unsigned int u = uf.u;
    unsigned int r = u + 0x7fffu + ((u >> 16) & 1u);
    return (u16)(r >> 16);
}

// ---------------- CSR build: histogram -> 3-phase parallel scan -> placement --------
__global__ __launch_bounds__(256) void hist_kernel(const int* __restrict__ keys, int n,
                                                   int* __restrict__ cnt) {
    int i = blockIdx.x * 256 + threadIdx.x;
    if (i < n) atomicAdd(&cnt[keys[i]], 1);
}

// Phase A: per-1024-chunk sums (48 blocks x 256 threads, int4 loads)
__global__ __launch_bounds__(256) void scanA_kernel(const int* __restrict__ cnt,
                                                    int* __restrict__ bsum) {
    int blk = blockIdx.x, t = threadIdx.x;
    int4 v = reinterpret_cast<const int4*>(cnt)[blk * 256 + t];
    int s = v.x + v.y + v.z + v.w;
    __shared__ int red[256];
    red[t] = s;
    __syncthreads();
    for (int o = 128; o > 0; o >>= 1) {
        if (t < o) red[t] += red[t + o];
        __syncthreads();
    }
    if (t == 0) bsum[blk] = red[0];
}

// Phase B: scan 48 chunk sums with segment resets (1 thread; launch-latency bound)
__global__ __launch_bounds__(64) void scanB_kernel(const int* __restrict__ bsum,
                                                   int* __restrict__ cbase) {
    if (threadIdx.x == 0) {
        int run = 0;
        for (int c = 0; c < SCAN_NCH; ++c) {
            if (c == SEG1_CH || c == SEG2_CH) run = 0;
            cbase[c] = run;
            run += bsum[c];
        }
    }
}

// Phase C: in-chunk exclusive scan + base, write rowptr/fill/totals
__global__ __launch_bounds__(256) void scanC_kernel(const int* __restrict__ cnt,
                                                    const int* __restrict__ cbase,
                                                    int* __restrict__ rowptr_e,
                                                    int* __restrict__ rowptr_v,
                                                    int* __restrict__ rowptr_s,
                                                    int* __restrict__ fill) {
    int blk = blockIdx.x, t = threadIdx.x;
    int gi = blk * 1024 + t * 4;
    int4 v = reinterpret_cast<const int4*>(cnt)[blk * 256 + t];
    int s0 = v.x, s1 = s0 + v.y, s2 = s1 + v.z, s3 = s2 + v.w;
    __shared__ int part[256];
    part[t] = s3;
    __syncthreads();
    for (int o = 1; o < 256; o <<= 1) {
        int a = (t >= o) ? part[t - o] : 0;
        __syncthreads();
        part[t] += a;
        __syncthreads();
    }
    int excl = (t > 0 ? part[t - 1] : 0) + cbase[blk];
    int4 e;
    e.x = excl; e.y = excl + s0; e.z = excl + s1; e.w = excl + s2;
    int* rp; int li;
    if (blk < SEG1_CH)      { rp = rowptr_e; li = gi; }
    else if (blk < SEG2_CH) { rp = rowptr_v; li = gi - NE_; }
    else                    { rp = rowptr_s; li = gi - NE_ - NV_; }
    rp[li + 0] = e.x; rp[li + 1] = e.y; rp[li + 2] = e.z; rp[li + 3] = e.w;
    reinterpret_cast<int4*>(fill)[blk * 256 + t] = e;
    if (t == 255) {
        int tot = excl + s3;
        if (blk == SEG1_CH - 1) rowptr_e[NE_] = tot;
        if (blk == SEG2_CH - 1) rowptr_v[NV_] = tot;
        if (blk == SCAN_NCH - 1) rowptr_s[NE_] = tot;
    }
}

__global__ __launch_bounds__(256) void place_kernel(const int* __restrict__ keys,
                                                    const int* __restrict__ other,
                                                    const float* __restrict__ vals, int n,
                                                    int* __restrict__ fill,
                                                    int* __restrict__ osrc,
                                                    float* __restrict__ oval,
                                                    const int* __restrict__ xmap,
                                                    int* __restrict__ osrc2) {
    int i = blockIdx.x * 256 + threadIdx.x;
    if (i >= n) return;
    int k = keys[i];
    int o = other[i];
    int p = atomicAdd(&fill[k], 1);
    osrc[p] = o;
    oval[p] = vals[i];
    if (osrc2) osrc2[p] = xmap[o];
}

// ---------------- 256-dim segment gather-sum (one wave per segment) -----------------
// dst[seg][:] = gscale[seg] * sum_k vals[k]*src[srcidx[k]][:]   (+bias,relu if EPI)
template <bool EPI>
__global__ __launch_bounds__(256) void gather256_kernel(const int* __restrict__ rowptr,
                                                        const int* __restrict__ srcidx,
                                                        const float* __restrict__ svals,
                                                        const float* __restrict__ src,
                                                        const float* __restrict__ gscale,
                                                        const float* __restrict__ bias,
                                                        float* __restrict__ dst, int nseg) {
    int seg = (blockIdx.x * 256 + threadIdx.x) >> 6;
    int lane = threadIdx.x & 63;
    if (seg >= nseg) return;
    int start = rowptr[seg], end = rowptr[seg + 1];
    const float4* src4 = reinterpret_cast<const float4*>(src);
    float4 acc = make_float4(0.f, 0.f, 0.f, 0.f);
    for (int k = start; k < end; ++k) {
        int r = srcidx[k];
        float v = svals[k];
        float4 sv = src4[(size_t)r * 64 + lane];
        acc.x += v * sv.x; acc.y += v * sv.y;
        acc.z += v * sv.z; acc.w += v * sv.w;
    }
    float sc = gscale ? gscale[seg] : 1.f;
    float4 o;
    o.x = sc * acc.x; o.y = sc * acc.y; o.z = sc * acc.z; o.w = sc * acc.w;
    if (EPI) {
        float4 bv = reinterpret_cast<const float4*>(bias)[lane];
        o.x = fmaxf(o.x + bv.x, 0.f); o.y = fmaxf(o.y + bv.y, 0.f);
        o.z = fmaxf(o.z + bv.z, 0.f); o.w = fmaxf(o.w + bv.w, 0.f);
    }
    reinterpret_cast<float4*>(dst)[(size_t)seg * 64 + lane] = o;
}

// ---------------- W -> transposed hi/lo bf16 split ----------------------------------
__global__ __launch_bounds__(256) void wconv_kernel(const float* __restrict__ W, int K, int KP,
                                                    u16* __restrict__ Wth, u16* __restrict__ Wtl) {
    int idx = blockIdx.x * 256 + threadIdx.x;
    if (idx >= 256 * KP) return;
    int n = idx & 255;
    int k = idx >> 8;
    float v = (k < K) ? W[(size_t)k * HID_ + n] : 0.f;
    u16 hi = f2bf(v);
    u16 lo = f2bf(v - bf2f(hi));
    Wth[(size_t)n * KP + k] = hi;
    Wtl[(size_t)n * KP + k] = lo;
}

// ---------------- split-bf16 MFMA GEMM: C[M][256] = A[M][K] @ Wt^T ------------------
template <bool EPI>
__global__ __launch_bounds__(256) void gemm_mfma_kernel(const float* __restrict__ A, int M,
                                                        int K, int Ks,
                                                        const u16* __restrict__ Bth,
                                                        const u16* __restrict__ Btl, int bstride,
                                                        const float* __restrict__ bias,
                                                        const float* __restrict__ degv,
                                                        float* __restrict__ C) {
    __shared__ __align__(16) u16 Ah[64 * 32];
    __shared__ __align__(16) u16 Al[64 * 32];
    __shared__ __align__(16) u16 Bh[64 * 32];
    __shared__ __align__(16) u16 Bl[64 * 32];
    int tid = threadIdx.x;
    int bm0 = blockIdx.x * 64, bn0 = blockIdx.y * 64;
    int w = tid >> 6, l = tid & 63;
    int srow = tid >> 2;
    int skbp = tid & 3;
    int skbl = skbp ^ ((srow >> 1) & 3);
    int arow = bm0 + srow; if (arow >= M) arow = M - 1;
    const float* Arow = A + (size_t)arow * Ks;
    const u16* Bhrow = Bth + (size_t)(bn0 + srow) * bstride;
    const u16* Blrow = Btl + (size_t)(bn0 + srow) * bstride;
    int sdst = srow * 32 + skbp * 8;
    int frow = w * 16 + (l & 15);
    int akbp = (l >> 4) ^ ((frow >> 1) & 3);
    const short8* afh = (const short8*)&Ah[frow * 32 + akbp * 8];
    const short8* afl = (const short8*)&Al[frow * 32 + akbp * 8];

    f32x4 acc[4] = {};
    int nkt = (K + 31) / 32;
    for (int kt = 0; kt < nkt; ++kt) {
        if (kt) __syncthreads();
        int kbase = kt * 32 + skbl * 8;
        float av[8];
        if (kbase + 8 <= K) {
            float4 v0 = *reinterpret_cast<const float4*>(Arow + kbase);
            float4 v1 = *reinterpret_cast<const float4*>(Arow + kbase + 4);
            av[0] = v0.x; av[1] = v0.y; av[2] = v0.z; av[3] = v0.w;
            av[4] = v1.x; av[5] = v1.y; av[6] = v1.z; av[7] = v1.w;
        } else {
#pragma unroll
            for (int e = 0; e < 8; ++e) {
                int kk = kbase + e;
                av[e] = (kk < K) ? Arow[kk] : 0.f;
            }
        }
        short8 h8, l8;
#pragma unroll
        for (int e = 0; e < 8; ++e) {
            u16 hi = f2bf(av[e]);
            h8[e] = (short)hi;
            l8[e] = (short)f2bf(av[e] - bf2f(hi));
        }
        *(short8*)&Ah[sdst] = h8;
        *(short8*)&Al[sdst] = l8;
        *(short8*)&Bh[sdst] = *(const short8*)(Bhrow + kt * 32 + skbl * 8);
        *(short8*)&Bl[sdst] = *(const short8*)(Blrow + kt * 32 + skbl * 8);
        __syncthreads();
        short8 ah = *afh;
        short8 al = *afl;
#pragma unroll
        for (int t = 0; t < 4; ++t) {
            int nrow = t * 16 + (l & 15);
            int bkbp = (l >> 4) ^ ((nrow >> 1) & 3);
            short8 tbh = *(const short8*)&Bh[nrow * 32 + bkbp * 8];
            short8 tbl = *(const short8*)&Bl[nrow * 32 + bkbp * 8];
            acc[t] = __builtin_amdgcn_mfma_f32_16x16x32_bf16(ah, tbh, acc[t], 0, 0, 0);
            acc[t] = __builtin_amdgcn_mfma_f32_16x16x32_bf16(al, tbh, acc[t], 0, 0, 0);
            acc[t] = __builtin_amdgcn_mfma_f32_16x16x32_bf16(ah, tbl, acc[t], 0, 0, 0);
        }
    }
#pragma unroll
    for (int r = 0; r < 4; ++r) {
        int row = bm0 + w * 16 + (l >> 4) * 4 + r;
        if (row >= M) continue;
        float dv = EPI ? degv[row] : 0.f;
#pragma unroll
        for (int t = 0; t < 4; ++t) {
            int col = bn0 + t * 16 + (l & 15);
            float v = acc[t][r];
            if (EPI) {
                v = v * dv + bias[col];
                v = v > 0.f ? v : 0.f;
            }
            C[(size_t)row * HID_ + col] = v;
        }
    }
}

// ---------------- attention logits (float4 dot) --------------------------------------
__global__ __launch_bounds__(256) void logits_kernel(const float* __restrict__ h, int dim,
                                                     int stride, const int* __restrict__ xidx,
                                                     const float* __restrict__ tfidf,
                                                     const float* __restrict__ attW,
                                                     const float* __restrict__ attb,
                                                     float* __restrict__ e) {
    int w = (blockIdx.x * 256 + threadIdx.x) >> 6;
    int lane = threadIdx.x & 63;
    if (w >= NV_) return;
    int row = xidx ? xidx[w] : w;
    const float4* hp = reinterpret_cast<const float4*>(h + (size_t)row * stride);
    const float4* aw = reinterpret_cast<const float4*>(attW);
    int nq = dim >> 2;
    float s = 0.f;
    for (int d4 = lane; d4 < nq; d4 += 64) {
        float4 a = hp[d4], b = aw[d4];
        s += a.x * b.x + a.y * b.y + a.z * b.z + a.w * b.w;
    }
#pragma unroll
    for (int off = 32; off > 0; off >>= 1) s += __shfl_down(s, off);
    if (lane == 0) {
        s += tfidf[w * 2] * attW[dim] + tfidf[w * 2 + 1] * attW[dim + 1] + attb[0];
        e[w] = s;
    }
}

// ---------------- global max of e ---------------------------------------------------
__global__ __launch_bounds__(1024) void gmax_kernel(const float* __restrict__ e,
                                                    float* __restrict__ gmax) {
    __shared__ float red[1024];
    float m = -3.4e38f;
    for (int i = threadIdx.x; i < NV_; i += 1024) m = fmaxf(m, e[i]);
    red[threadIdx.x] = m;
    __syncthreads();
    for (int s = 512; s > 0; s >>= 1) {
        if (threadIdx.x < (unsigned)s) red[threadIdx.x] = fmaxf(red[threadIdx.x], red[threadIdx.x + s]);
        __syncthreads();
    }
    if (threadIdx.x == 0) gmax[0] = red[0];
}

// ---------------- pool stage A: normalized softmax weights per node -----------------
__global__ __launch_bounds__(512) void weights_kernel(const float* __restrict__ e,
                                                      const float* __restrict__ gmax,
                                                      float* __restrict__ w) {
    int b = blockIdx.x;
    int t = threadIdx.x;
    int node = b * N_ + t;
    float wv = expf(e[node] - gmax[0]);
    __shared__ float red[512];
    red[t] = wv;
    __syncthreads();
    for (int s = 256; s > 0; s >>= 1) {
        if (t < s) red[t] += red[t + s];
        __syncthreads();
    }
    float inv = 1.f / (red[0] + 1e-10f);
    w[node] = wv * inv;
}

// ---------------- pool stage B: partial weighted-sum + max over 64-node chunks ------
__global__ __launch_bounds__(256) void pool_partial_kernel(const float* __restrict__ h, int dim,
                                                           int stride, const int* __restrict__ xidx,
                                                           const float* __restrict__ w,
                                                           float* __restrict__ psum,
                                                           float* __restrict__ pmax) {
    int b = blockIdx.x, c = blockIdx.y;
    __shared__ int rows[PVN];
    __shared__ float wv[PVN];
    int t = threadIdx.x;
    if (t < PVN) {
        int node = b * N_ + c * PVN + t;
        rows[t] = xidx ? xidx[node] : node;
        wv[t] = w[node];
    }
    __syncthreads();
    float s0 = 0.f, s1 = 0.f, m0 = -3.4e38f, m1 = -3.4e38f;
    int d0 = t, d1 = t + 256;
    bool has1 = d1 < dim;
    for (int i = 0; i < PVN; ++i) {
        const float* hp = h + (size_t)rows[i] * stride;
        float ww = wv[i];
        float x0 = hp[d0];
        s0 += ww * x0;
        m0 = fmaxf(m0, x0);
        if (has1) {
            float x1 = hp[d1];
            s1 += ww * x1;
            m1 = fmaxf(m1, x1);
        }
    }
    size_t base = ((size_t)b * PCHUNK + c) * dim;
    psum[base + d0] = s0;
    pmax[base + d0] = m0;
    if (has1) {
        psum[base + d1] = s1;
        pmax[base + d1] = m1;
    }
}

// ---------------- pool stage C: combine chunk partials -------------------------------
__global__ __launch_bounds__(256) void pool_combine_kernel(const float* __restrict__ psum,
                                                           const float* __restrict__ pmax,
                                                           int dim, float* __restrict__ p) {
    int b = blockIdx.x;
    for (int d = threadIdx.x; d < dim; d += 256) {
        float s = 0.f, m = -3.4e38f;
        for (int c = 0; c < PCHUNK; ++c) {
            size_t base = ((size_t)b * PCHUNK + c) * dim;
            s += psum[base + d];
            m = fmaxf(m, pmax[base + d]);
        }
        p[(size_t)b * 2 * dim + d] = s;
        p[(size_t)b * 2 * dim + dim + d] = m;
    }
}

// ---------------- final prediction ---------------------------------------------------
__global__ __launch_bounds__(64) void final_kernel(const float* p0, const float* p1, const float* p2,
                                                   const float* pW0, const float* pb0,
                                                   const float* pW1, const float* pb1,
                                                   const float* pW2, const float* pb2, float* out) {
    int b = blockIdx.x;
    int c = threadIdx.x;
    if (c >= NC_) return;
    float s = pb0[c] + pb1[c] + pb2[c];
    for (int k = 0; k < 2 * D_; ++k) s += p0[(size_t)b * 2 * D_ + k] * pW0[k * NC_ + c];
    for (int k = 0; k < 2 * HID_; ++k) s += p1[(size_t)b * 2 * HID_ + k] * pW1[k * NC_ + c];
    for (int k = 0; k < 2 * HID_; ++k) s += p2[(size_t)b * 2 * HID_ + k] * pW2[k * NC_ + c];
    out[b * NC_ + c] = s;
}

extern "C" void kernel_launch(void* const* d_in, const int* in_sizes, int n_in,
                              void* d_out, int out_size, void* d_ws, size_t ws_size,
                              hipStream_t stream) {
    const int*   x         = (const int*)d_in[0];
    const int*   inc_rows  = (const int*)d_in[1];
    const int*   inc_cols  = (const int*)d_in[2];
    const float* inc_vals  = (const float*)d_in[3];
    const int*   sent_rows = (const int*)d_in[4];
    const int*   sent_cols = (const int*)d_in[5];
    const float* sent_vals = (const float*)d_in[6];
    const float* deg_v     = (const float*)d_in[7];
    const float* deg_e     = (const float*)d_in[8];
    const float* tf_idf = (const float*)d_in[11];
    const float* emb    = (const float*)d_in[12];
    const float* W1 = (const float*)d_in[13];
    const float* b1 = (const float*)d_in[14];
    const float* W2 = (const float*)d_in[15];
    const float* b2 = (const float*)d_in[16];
    const float* attW0 = (const float*)d_in[17];
    const float* attb0 = (const float*)d_in[18];
    const float* attW1 = (const float*)d_in[19];
    const float* attb1 = (const float*)d_in[20];
    const float* attW2 = (const float*)d_in[21];
    const float* attb2 = (const float*)d_in[22];
    const float* pW0 = (const float*)d_in[23];
    const float* pb0 = (const float*)d_in[24];
    const float* pW1 = (const float*)d_in[25];
    const float* pb1 = (const float*)d_in[26];
    const float* pW2 = (const float*)d_in[27];
    const float* pb2 = (const float*)d_in[28];
    float* out = (float*)d_out;

    const int VOCAB = 30000;

    // workspace layout
    char* ws = (char*)d_ws;
    size_t off = 0;
    auto alloc = [&](size_t bytes) {
        void* p = ws + off;
        off += (bytes + 255) & ~(size_t)255;
        return p;
    };
    float* EW = (float*)alloc((size_t)VOCAB * HID_ * sizeof(float)); // emb @ W1
    float* hv = (float*)alloc((size_t)NV_ * HID_ * sizeof(float));
    float* m  = (float*)alloc((size_t)NE_ * HID_ * sizeof(float));
    float* m2 = (float*)alloc((size_t)NE_ * HID_ * sizeof(float));
    float* h1 = (float*)alloc((size_t)NV_ * HID_ * sizeof(float));
    float* h2 = (float*)alloc((size_t)NV_ * HID_ * sizeof(float));
    u16* Wt1h = (u16*)alloc((size_t)HID_ * 320 * sizeof(u16));
    u16* Wt1l = (u16*)alloc((size_t)HID_ * 320 * sizeof(u16));
    u16* Wt2h = (u16*)alloc((size_t)HID_ * 256 * sizeof(u16));
    u16* Wt2l = (u16*)alloc((size_t)HID_ * 256 * sizeof(u16));
    float* e  = (float*)alloc((size_t)NV_ * sizeof(float));
    float* gmax = (float*)alloc(256);
    float* watt = (float*)alloc((size_t)NV_ * sizeof(float));
    float* psum = (float*)alloc((size_t)B_ * PCHUNK * D_ * sizeof(float));
    float* pmax = (float*)alloc((size_t)B_ * PCHUNK * D_ * sizeof(float));
    float* p0 = (float*)alloc((size_t)B_ * 2 * D_ * sizeof(float));
    float* p1 = (float*)alloc((size_t)B_ * 2 * HID_ * sizeof(float));
    float* p2 = (float*)alloc((size_t)B_ * 2 * HID_ * sizeof(float));
    // CSR structures
    int* cnt      = (int*)alloc((size_t)SCAN_TOT * sizeof(int));  // [cnt_e|cnt_v|cnt_s]
    int* fill     = (int*)alloc((size_t)SCAN_TOT * sizeof(int));  // same layout
    int* cnt_e = cnt;
    int* cnt_v = cnt + NE_;
    int* cnt_s = cnt + NE_ + NV_;
    int* fill_e = fill;
    int* fill_v = fill + NE_;
    int* fill_s = fill + NE_ + NV_;
    int* rowptr_e = (int*)alloc((size_t)(NE_ + 1) * sizeof(int));
    int* rowptr_v = (int*)alloc((size_t)(NV_ + 1) * sizeof(int));
    int* rowptr_s = (int*)alloc((size_t)(NE_ + 1) * sizeof(int));
    int* bsum  = (int*)alloc((size_t)SCAN_NCH * sizeof(int));
    int* cbase = (int*)alloc((size_t)SCAN_NCH * sizeof(int));
    int*   srcA_e = (int*)  alloc((size_t)NNZ_ * sizeof(int));  // node ids (layer 2)
    int*   srcX_e = (int*)  alloc((size_t)NNZ_ * sizeof(int));  // x[node] ids (layer 1)
    float* val_e  = (float*)alloc((size_t)NNZ_ * sizeof(float));
    int*   srcA_v = (int*)  alloc((size_t)NNZ_ * sizeof(int));
    float* val_v  = (float*)alloc((size_t)NNZ_ * sizeof(float));
    int*   srcA_s = (int*)  alloc((size_t)SNNZ_ * sizeof(int));
    float* val_s  = (float*)alloc((size_t)SNNZ_ * sizeof(float));

    // ---- build CSR ----
    hipMemsetAsync(cnt, 0, (size_t)SCAN_TOT * sizeof(int), stream);
    hist_kernel<<<NNZ_ / 256, 256, 0, stream>>>(inc_cols, NNZ_, cnt_e);
    hist_kernel<<<NNZ_ / 256, 256, 0, stream>>>(inc_rows, NNZ_, cnt_v);
    hist_kernel<<<SNNZ_ / 256, 256, 0, stream>>>(sent_cols, SNNZ_, cnt_s);
    scanA_kernel<<<SCAN_NCH, 256, 0, stream>>>(cnt, bsum);
    scanB_kernel<<<1, 64, 0, stream>>>(bsum, cbase);
    scanC_kernel<<<SCAN_NCH, 256, 0, stream>>>(cnt, cbase, rowptr_e, rowptr_v, rowptr_s, fill);
    place_kernel<<<NNZ_ / 256, 256, 0, stream>>>(inc_cols, inc_rows, inc_vals, NNZ_,
                                                 fill_e, srcA_e, val_e, x, srcX_e);
    place_kernel<<<NNZ_ / 256, 256, 0, stream>>>(inc_rows, inc_cols, inc_vals, NNZ_,
                                                 fill_v, srcA_v, val_v, nullptr, nullptr);
    place_kernel<<<SNNZ_ / 256, 256, 0, stream>>>(sent_cols, sent_rows, sent_vals, SNNZ_,
                                                  fill_s, srcA_s, val_s, nullptr, nullptr);

    // ---- weight conversion (transpose + bf16 hi/lo split) ----
    wconv_kernel<<<(256 * 320 + 255) / 256, 256, 0, stream>>>(W1, D_, 320, Wt1h, Wt1l);
    wconv_kernel<<<(256 * 256 + 255) / 256, 256, 0, stream>>>(W2, HID_, 256, Wt2h, Wt2l);

    // ---- EW = emb @ W1  (vocab-side GEMM; layer-1 linear hoisted before sparse chain)
    {
        dim3 grid((VOCAB + 63) / 64, HID_ / 64);
        gemm_mfma_kernel<false><<<grid, 256, 0, stream>>>(emb, VOCAB, D_, D_,
                                                          Wt1h, Wt1l, 320,
                                                          nullptr, nullptr, EW);
    }

    // ---- layer 1 sparse chain @ dim 256 ----
    gather256_kernel<false><<<NE_ / 4, 256, 0, stream>>>(rowptr_e, srcX_e, val_e,
                                                         EW, deg_e, nullptr, m, NE_);
    gather256_kernel<false><<<NE_ / 4, 256, 0, stream>>>(rowptr_s, srcA_s, val_s,
                                                         m, nullptr, nullptr, m2, NE_);
    gather256_kernel<true><<<NV_ / 4, 256, 0, stream>>>(rowptr_v, srcA_v, val_v,
                                                        m2, deg_v, b1, h1, NV_);

    // ---- layer 2 ----
    gather256_kernel<false><<<NE_ / 4, 256, 0, stream>>>(rowptr_e, srcA_e, val_e,
                                                         h1, deg_e, nullptr, m, NE_);
    gather256_kernel<false><<<NE_ / 4, 256, 0, stream>>>(rowptr_s, srcA_s, val_s,
                                                         m, nullptr, nullptr, m2, NE_);
    gather256_kernel<false><<<NV_ / 4, 256, 0, stream>>>(rowptr_v, srcA_v, val_v,
                                                         m2, nullptr, nullptr, hv, NV_);
    {
        dim3 grid(NV_ / 64, HID_ / 64);
        gemm_mfma_kernel<true><<<grid, 256, 0, stream>>>(hv, NV_, HID_, HID_,
                                                         Wt2h, Wt2l, 256,
                                                         b2, deg_v, h2);
    }

    // ---- pools ----
    dim3 pgrid(B_, PCHUNK);
    logits_kernel<<<NV_ / 4, 256, 0, stream>>>(emb, D_, D_, x, tf_idf, attW0, attb0, e);
    gmax_kernel<<<1, 1024, 0, stream>>>(e, gmax);
    weights_kernel<<<B_, 512, 0, stream>>>(e, gmax, watt);
    pool_partial_kernel<<<pgrid, 256, 0, stream>>>(emb, D_, D_, x, watt, psum, pmax);
    pool_combine_kernel<<<B_, 256, 0, stream>>>(psum, pmax, D_, p0);

    logits_kernel<<<NV_ / 4, 256, 0, stream>>>(h1, HID_, HID_, nullptr, tf_idf, attW1, attb1, e);
    gmax_kernel<<<1, 1024, 0, stream>>>(e, gmax);
    weights_kernel<<<B_, 512, 0, stream>>>(e, gmax, watt);
    pool_partial_kernel<<<pgrid, 256, 0, stream>>>(h1, HID_, HID_, nullptr, watt, psum, pmax);
    pool_combine_kernel<<<B_, 256, 0, stream>>>(psum, pmax, HID_, p1);

    logits_kernel<<<NV_ / 4, 256, 0, stream>>>(h2, HID_, HID_, nullptr, tf_idf, attW2, attb2, e);
    gmax_kernel<<<1, 1024, 0, stream>>>(e, gmax);
    weights_kernel<<<B_, 512, 0, stream>>>(e, gmax, watt);
    pool_partial_kernel<<<pgrid, 256, 0, stream>>>(h2, HID_, HID_, nullptr, watt, psum, pmax);
    pool_combine_kernel<<<B_, 256, 0, stream>>>(psum, pmax, HID_, p2);

    // ---- final linear ----
    final_kernel<<<B_, 64, 0, stream>>>(p0, p1, p2, pW0, pb0, pW1, pb1, pW2, pb2, out);
}

// Round 7
// 411.431 us; speedup vs baseline: 3.6033x; 1.2088x over previous
//
#include <hip/hip_runtime.h>
#include <cstddef>

#define B_   64
#define N_   512
#define NV_  32768
#define NE_  8192
#define NNZ_ 262144
#define SNNZ_ 24576
#define D_   300
#define HID_ 256
#define NC_  10
#define PCHUNK 8
#define PVN (N_ / PCHUNK)   // 64 nodes per pool chunk

#define SCAN_TOT (NE_ + NV_ + NE_)      // 49152 counts, contiguous [cnt_e|cnt_v|cnt_s]
#define SCAN_NCH (SCAN_TOT / 1024)      // 48 chunks
#define SEG1_CH  (NE_ / 1024)           // 8  (start of cnt_v chunks)
#define SEG2_CH  ((NE_ + NV_) / 1024)   // 40 (start of cnt_s chunks)

using u16 = unsigned short;
typedef __attribute__((ext_vector_type(8))) short short8;
typedef __attribute__((ext_vector_type(4))) float f32x4;

__device__ __forceinline__ float bf2f(u16 v) {
    union { unsigned int u; float f; } uf;
    uf.u = ((unsigned int)v) << 16;
    return uf.f;
}
__device__ __forceinline__ u16 f2bf(float f) {
    union { float f; unsigned int u; } uf; uf.f = f;
    unsigned int u = uf.u;
    unsigned int r = u + 0x7fffu + ((u >> 16) & 1u);
    return (u16)(r >> 16);
}

// ---------------- CSR build: histogram -> 3-phase parallel scan -> placement --------
__global__ __launch_bounds__(256) void hist_kernel(const int* __restrict__ keys, int n,
                                                   int* __restrict__ cnt) {
    int i = blockIdx.x * 256 + threadIdx.x;
    if (i < n) atomicAdd(&cnt[keys[i]], 1);
}

// Phase A: per-1024-chunk sums (48 blocks x 256 threads, int4 loads)
__global__ __launch_bounds__(256) void scanA_kernel(const int* __restrict__ cnt,
                                                    int* __restrict__ bsum) {
    int blk = blockIdx.x, t = threadIdx.x;
    int4 v = reinterpret_cast<const int4*>(cnt)[blk * 256 + t];
    int s = v.x + v.y + v.z + v.w;
    __shared__ int red[256];
    red[t] = s;
    __syncthreads();
    for (int o = 128; o > 0; o >>= 1) {
        if (t < o) red[t] += red[t + o];
        __syncthreads();
    }
    if (t == 0) bsum[blk] = red[0];
}

// Phase B: scan 48 chunk sums with segment resets (1 thread; launch-latency bound)
__global__ __launch_bounds__(64) void scanB_kernel(const int* __restrict__ bsum,
                                                   int* __restrict__ cbase) {
    if (threadIdx.x == 0) {
        int run = 0;
        for (int c = 0; c < SCAN_NCH; ++c) {
            if (c == SEG1_CH || c == SEG2_CH) run = 0;
            cbase[c] = run;
            run += bsum[c];
        }
    }
}

// Phase C: in-chunk exclusive scan + base, write rowptr/fill/totals
__global__ __launch_bounds__(256) void scanC_kernel(const int* __restrict__ cnt,
                                                    const int* __restrict__ cbase,
                                                    int* __restrict__ rowptr_e,
                                                    int* __restrict__ rowptr_v,
                                                    int* __restrict__ rowptr_s,
                                                    int* __restrict__ fill) {
    int blk = blockIdx.x, t = threadIdx.x;
    int gi = blk * 1024 + t * 4;
    int4 v = reinterpret_cast<const int4*>(cnt)[blk * 256 + t];
    int s0 = v.x, s1 = s0 + v.y, s2 = s1 + v.z, s3 = s2 + v.w;
    __shared__ int part[256];
    part[t] = s3;
    __syncthreads();
    for (int o = 1; o < 256; o <<= 1) {
        int a = (t >= o) ? part[t - o] : 0;
        __syncthreads();
        part[t] += a;
        __syncthreads();
    }
    int excl = (t > 0 ? part[t - 1] : 0) + cbase[blk];
    int4 e;
    e.x = excl; e.y = excl + s0; e.z = excl + s1; e.w = excl + s2;
    int* rp; int li;
    if (blk < SEG1_CH)      { rp = rowptr_e; li = gi; }
    else if (blk < SEG2_CH) { rp = rowptr_v; li = gi - NE_; }
    else                    { rp = rowptr_s; li = gi - NE_ - NV_; }
    rp[li + 0] = e.x; rp[li + 1] = e.y; rp[li + 2] = e.z; rp[li + 3] = e.w;
    reinterpret_cast<int4*>(fill)[blk * 256 + t] = e;
    if (t == 255) {
        int tot = excl + s3;
        if (blk == SEG1_CH - 1) rowptr_e[NE_] = tot;
        if (blk == SEG2_CH - 1) rowptr_v[NV_] = tot;
        if (blk == SCAN_NCH - 1) rowptr_s[NE_] = tot;
    }
}

__global__ __launch_bounds__(256) void place_kernel(const int* __restrict__ keys,
                                                    const int* __restrict__ other,
                                                    const float* __restrict__ vals, int n,
                                                    int* __restrict__ fill,
                                                    int* __restrict__ osrc,
                                                    float* __restrict__ oval,
                                                    const int* __restrict__ xmap,
                                                    int* __restrict__ osrc2) {
    int i = blockIdx.x * 256 + threadIdx.x;
    if (i >= n) return;
    int k = keys[i];
    int o = other[i];
    int p = atomicAdd(&fill[k], 1);
    osrc[p] = o;
    oval[p] = vals[i];
    if (osrc2) osrc2[p] = xmap[o];
}

// ---------------- 256-dim segment gather-sum (one wave per segment) -----------------
// dst[seg][:] = gscale[seg] * sum_k vals[k]*src[srcidx[k]][:]   (+bias,relu if EPI)
template <bool EPI>
__global__ __launch_bounds__(256) void gather256_kernel(const int* __restrict__ rowptr,
                                                        const int* __restrict__ srcidx,
                                                        const float* __restrict__ svals,
                                                        const float* __restrict__ src,
                                                        const float* __restrict__ gscale,
                                                        const float* __restrict__ bias,
                                                        float* __restrict__ dst, int nseg) {
    int seg = (blockIdx.x * 256 + threadIdx.x) >> 6;
    int lane = threadIdx.x & 63;
    if (seg >= nseg) return;
    int start = rowptr[seg], end = rowptr[seg + 1];
    const float4* src4 = reinterpret_cast<const float4*>(src);
    float4 acc = make_float4(0.f, 0.f, 0.f, 0.f);
    for (int k = start; k < end; ++k) {
        int r = srcidx[k];
        float v = svals[k];
        float4 sv = src4[(size_t)r * 64 + lane];
        acc.x += v * sv.x; acc.y += v * sv.y;
        acc.z += v * sv.z; acc.w += v * sv.w;
    }
    float sc = gscale ? gscale[seg] : 1.f;
    float4 o;
    o.x = sc * acc.x; o.y = sc * acc.y; o.z = sc * acc.z; o.w = sc * acc.w;
    if (EPI) {
        float4 bv = reinterpret_cast<const float4*>(bias)[lane];
        o.x = fmaxf(o.x + bv.x, 0.f); o.y = fmaxf(o.y + bv.y, 0.f);
        o.z = fmaxf(o.z + bv.z, 0.f); o.w = fmaxf(o.w + bv.w, 0.f);
    }
    reinterpret_cast<float4*>(dst)[(size_t)seg * 64 + lane] = o;
}

// ---------------- W -> transposed hi/lo bf16 split ----------------------------------
__global__ __launch_bounds__(256) void wconv_kernel(const float* __restrict__ W, int K, int KP,
                                                    u16* __restrict__ Wth, u16* __restrict__ Wtl) {
    int idx = blockIdx.x * 256 + threadIdx.x;
    if (idx >= 256 * KP) return;
    int n = idx & 255;
    int k = idx >> 8;
    float v = (k < K) ? W[(size_t)k * HID_ + n] : 0.f;
    u16 hi = f2bf(v);
    u16 lo = f2bf(v - bf2f(hi));
    Wth[(size_t)n * KP + k] = hi;
    Wtl[(size_t)n * KP + k] = lo;
}

// ---------------- split-bf16 MFMA GEMM: C[M][256] = A[M][K] @ Wt^T ------------------
template <bool EPI>
__global__ __launch_bounds__(256) void gemm_mfma_kernel(const float* __restrict__ A, int M,
                                                        int K, int Ks,
                                                        const u16* __restrict__ Bth,
                                                        const u16* __restrict__ Btl, int bstride,
                                                        const float* __restrict__ bias,
                                                        const float* __restrict__ degv,
                                                        float* __restrict__ C) {
    __shared__ __align__(16) u16 Ah[64 * 32];
    __shared__ __align__(16) u16 Al[64 * 32];
    __shared__ __align__(16) u16 Bh[64 * 32];
    __shared__ __align__(16) u16 Bl[64 * 32];
    int tid = threadIdx.x;
    int bm0 = blockIdx.x * 64, bn0 = blockIdx.y * 64;
    int w = tid >> 6, l = tid & 63;
    int srow = tid >> 2;
    int skbp = tid & 3;
    int skbl = skbp ^ ((srow >> 1) & 3);
    int arow = bm0 + srow; if (arow >= M) arow = M - 1;
    const float* Arow = A + (size_t)arow * Ks;
    const u16* Bhrow = Bth + (size_t)(bn0 + srow) * bstride;
    const u16* Blrow = Btl + (size_t)(bn0 + srow) * bstride;
    int sdst = srow * 32 + skbp * 8;
    int frow = w * 16 + (l & 15);
    int akbp = (l >> 4) ^ ((frow >> 1) & 3);
    const short8* afh = (const short8*)&Ah[frow * 32 + akbp * 8];
    const short8* afl = (const short8*)&Al[frow * 32 + akbp * 8];

    f32x4 acc[4] = {};
    int nkt = (K + 31) / 32;
    for (int kt = 0; kt < nkt; ++kt) {
        if (kt) __syncthreads();
        int kbase = kt * 32 + skbl * 8;
        float av[8];
        if (kbase + 8 <= K) {
            float4 v0 = *reinterpret_cast<const float4*>(Arow + kbase);
            float4 v1 = *reinterpret_cast<const float4*>(Arow + kbase + 4);
            av[0] = v0.x; av[1] = v0.y; av[2] = v0.z; av[3] = v0.w;
            av[4] = v1.x; av[5] = v1.y; av[6] = v1.z; av[7] = v1.w;
        } else {
#pragma unroll
            for (int e = 0; e < 8; ++e) {
                int kk = kbase + e;
                av[e] = (kk < K) ? Arow[kk] : 0.f;
            }
        }
        short8 h8, l8;
#pragma unroll
        for (int e = 0; e < 8; ++e) {
            u16 hi = f2bf(av[e]);
            h8[e] = (short)hi;
            l8[e] = (short)f2bf(av[e] - bf2f(hi));
        }
        *(short8*)&Ah[sdst] = h8;
        *(short8*)&Al[sdst] = l8;
        *(short8*)&Bh[sdst] = *(const short8*)(Bhrow + kt * 32 + skbl * 8);
        *(short8*)&Bl[sdst] = *(const short8*)(Blrow + kt * 32 + skbl * 8);
        __syncthreads();
        short8 ah = *afh;
        short8 al = *afl;
#pragma unroll
        for (int t = 0; t < 4; ++t) {
            int nrow = t * 16 + (l & 15);
            int bkbp = (l >> 4) ^ ((nrow >> 1) & 3);
            short8 tbh = *(const short8*)&Bh[nrow * 32 + bkbp * 8];
            short8 tbl = *(const short8*)&Bl[nrow * 32 + bkbp * 8];
            acc[t] = __builtin_amdgcn_mfma_f32_16x16x32_bf16(ah, tbh, acc[t], 0, 0, 0);
            acc[t] = __builtin_amdgcn_mfma_f32_16x16x32_bf16(al, tbh, acc[t], 0, 0, 0);
            acc[t] = __builtin_amdgcn_mfma_f32_16x16x32_bf16(ah, tbl, acc[t], 0, 0, 0);
        }
    }
#pragma unroll
    for (int r = 0; r < 4; ++r) {
        int row = bm0 + w * 16 + (l >> 4) * 4 + r;
        if (row >= M) continue;
        float dv = EPI ? degv[row] : 0.f;
#pragma unroll
        for (int t = 0; t < 4; ++t) {
            int col = bn0 + t * 16 + (l & 15);
            float v = acc[t][r];
            if (EPI) {
                v = v * dv + bias[col];
                v = v > 0.f ? v : 0.f;
            }
            C[(size_t)row * HID_ + col] = v;
        }
    }
}

// ---------------- attention logits (float4 dot) --------------------------------------
__global__ __launch_bounds__(256) void logits_kernel(const float* __restrict__ h, int dim,
                                                     int stride, const int* __restrict__ xidx,
                                                     const float* __restrict__ tfidf,
                                                     const float* __restrict__ attW,
                                                     const float* __restrict__ attb,
                                                     float* __restrict__ e) {
    int w = (blockIdx.x * 256 + threadIdx.x) >> 6;
    int lane = threadIdx.x & 63;
    if (w >= NV_) return;
    int row = xidx ? xidx[w] : w;
    const float4* hp = reinterpret_cast<const float4*>(h + (size_t)row * stride);
    const float4* aw = reinterpret_cast<const float4*>(attW);
    int nq = dim >> 2;
    float s = 0.f;
    for (int d4 = lane; d4 < nq; d4 += 64) {
        float4 a = hp[d4], b = aw[d4];
        s += a.x * b.x + a.y * b.y + a.z * b.z + a.w * b.w;
    }
#pragma unroll
    for (int off = 32; off > 0; off >>= 1) s += __shfl_down(s, off);
    if (lane == 0) {
        s += tfidf[w * 2] * attW[dim] + tfidf[w * 2 + 1] * attW[dim + 1] + attb[0];
        e[w] = s;
    }
}

// ---------------- pool stage A: per-graph softmax weights (per-graph max) -----------
// exp(e - max_b) / (sum + 1e-10); max_b per graph — cancels vs global max in the ratio
__global__ __launch_bounds__(512) void weights_kernel(const float* __restrict__ e,
                                                      float* __restrict__ w) {
    int b = blockIdx.x;
    int t = threadIdx.x;
    int node = b * N_ + t;
    float ev = e[node];
    __shared__ float red[512];
    red[t] = ev;
    __syncthreads();
    for (int s = 256; s > 0; s >>= 1) {
        if (t < s) red[t] = fmaxf(red[t], red[t + s]);
        __syncthreads();
    }
    float mx = red[0];
    __syncthreads();
    float wv = expf(ev - mx);
    red[t] = wv;
    __syncthreads();
    for (int s = 256; s > 0; s >>= 1) {
        if (t < s) red[t] += red[t + s];
        __syncthreads();
    }
    float inv = 1.f / (red[0] + 1e-10f);
    w[node] = wv * inv;
}

// ---------------- pool stage B: partial weighted-sum + max over 64-node chunks ------
__global__ __launch_bounds__(256) void pool_partial_kernel(const float* __restrict__ h, int dim,
                                                           int stride, const int* __restrict__ xidx,
                                                           const float* __restrict__ w,
                                                           float* __restrict__ psum,
                                                           float* __restrict__ pmax) {
    int b = blockIdx.x, c = blockIdx.y;
    __shared__ int rows[PVN];
    __shared__ float wv[PVN];
    int t = threadIdx.x;
    if (t < PVN) {
        int node = b * N_ + c * PVN + t;
        rows[t] = xidx ? xidx[node] : node;
        wv[t] = w[node];
    }
    __syncthreads();
    float s0 = 0.f, s1 = 0.f, m0 = -3.4e38f, m1 = -3.4e38f;
    int d0 = t, d1 = t + 256;
    bool has1 = d1 < dim;
    for (int i = 0; i < PVN; ++i) {
        const float* hp = h + (size_t)rows[i] * stride;
        float ww = wv[i];
        float x0 = hp[d0];
        s0 += ww * x0;
        m0 = fmaxf(m0, x0);
        if (has1) {
            float x1 = hp[d1];
            s1 += ww * x1;
            m1 = fmaxf(m1, x1);
        }
    }
    size_t base = ((size_t)b * PCHUNK + c) * dim;
    psum[base + d0] = s0;
    pmax[base + d0] = m0;
    if (has1) {
        psum[base + d1] = s1;
        pmax[base + d1] = m1;
    }
}

// ---------------- pool stage C: combine chunk partials -------------------------------
__global__ __launch_bounds__(256) void pool_combine_kernel(const float* __restrict__ psum,
                                                           const float* __restrict__ pmax,
                                                           int dim, float* __restrict__ p) {
    int b = blockIdx.x;
    for (int d = threadIdx.x; d < dim; d += 256) {
        float s = 0.f, m = -3.4e38f;
        for (int c = 0; c < PCHUNK; ++c) {
            size_t base = ((size_t)b * PCHUNK + c) * dim;
            s += psum[base + d];
            m = fmaxf(m, pmax[base + d]);
        }
        p[(size_t)b * 2 * dim + d] = s;
        p[(size_t)b * 2 * dim + dim + d] = m;
    }
}

// ---------------- final prediction (parallel GEMV, 256 thr/graph) --------------------
__global__ __launch_bounds__(256) void final_kernel(const float* __restrict__ p0,
                                                    const float* __restrict__ p1,
                                                    const float* __restrict__ p2,
                                                    const float* __restrict__ pW0,
                                                    const float* __restrict__ pb0,
                                                    const float* __restrict__ pW1,
                                                    const float* __restrict__ pb1,
                                                    const float* __restrict__ pW2,
                                                    const float* __restrict__ pb2,
                                                    float* __restrict__ out) {
    int b = blockIdx.x;
    int t = threadIdx.x;
    int lane = t & 63, wv = t >> 6;
    float acc[NC_] = {};
    for (int k = t; k < 2 * D_; k += 256) {
        float pv = p0[(size_t)b * 2 * D_ + k];
        const float* wp = pW0 + (size_t)k * NC_;
#pragma unroll
        for (int c = 0; c < NC_; ++c) acc[c] += pv * wp[c];
    }
    for (int k = t; k < 2 * HID_; k += 256) {
        float pv = p1[(size_t)b * 2 * HID_ + k];
        const float* wp = pW1 + (size_t)k * NC_;
#pragma unroll
        for (int c = 0; c < NC_; ++c) acc[c] += pv * wp[c];
    }
    for (int k = t; k < 2 * HID_; k += 256) {
        float pv = p2[(size_t)b * 2 * HID_ + k];
        const float* wp = pW2 + (size_t)k * NC_;
#pragma unroll
        for (int c = 0; c < NC_; ++c) acc[c] += pv * wp[c];
    }
    __shared__ float red[4][NC_];
#pragma unroll
    for (int c = 0; c < NC_; ++c) {
        float s = acc[c];
#pragma unroll
        for (int off = 32; off > 0; off >>= 1) s += __shfl_down(s, off);
        if (lane == 0) red[wv][c] = s;
    }
    __syncthreads();
    if (t < NC_) {
        float s = red[0][t] + red[1][t] + red[2][t] + red[3][t];
        out[b * NC_ + t] = s + pb0[t] + pb1[t] + pb2[t];
    }
}

extern "C" void kernel_launch(void* const* d_in, const int* in_sizes, int n_in,
                              void* d_out, int out_size, void* d_ws, size_t ws_size,
                              hipStream_t stream) {
    const int*   x         = (const int*)d_in[0];
    const int*   inc_rows  = (const int*)d_in[1];
    const int*   inc_cols  = (const int*)d_in[2];
    const float* inc_vals  = (const float*)d_in[3];
    const int*   sent_rows = (const int*)d_in[4];
    const int*   sent_cols = (const int*)d_in[5];
    const float* sent_vals = (const float*)d_in[6];
    const float* deg_v     = (const float*)d_in[7];
    const float* deg_e     = (const float*)d_in[8];
    const float* tf_idf = (const float*)d_in[11];
    const float* emb    = (const float*)d_in[12];
    const float* W1 = (const float*)d_in[13];
    const float* b1 = (const float*)d_in[14];
    const float* W2 = (const float*)d_in[15];
    const float* b2 = (const float*)d_in[16];
    const float* attW0 = (const float*)d_in[17];
    const float* attb0 = (const float*)d_in[18];
    const float* attW1 = (const float*)d_in[19];
    const float* attb1 = (const float*)d_in[20];
    const float* attW2 = (const float*)d_in[21];
    const float* attb2 = (const float*)d_in[22];
    const float* pW0 = (const float*)d_in[23];
    const float* pb0 = (const float*)d_in[24];
    const float* pW1 = (const float*)d_in[25];
    const float* pb1 = (const float*)d_in[26];
    const float* pW2 = (const float*)d_in[27];
    const float* pb2 = (const float*)d_in[28];
    float* out = (float*)d_out;

    const int VOCAB = 30000;

    // workspace layout
    char* ws = (char*)d_ws;
    size_t off = 0;
    auto alloc = [&](size_t bytes) {
        void* p = ws + off;
        off += (bytes + 255) & ~(size_t)255;
        return p;
    };
    float* EW = (float*)alloc((size_t)VOCAB * HID_ * sizeof(float)); // emb @ W1
    float* hv = (float*)alloc((size_t)NV_ * HID_ * sizeof(float));
    float* m  = (float*)alloc((size_t)NE_ * HID_ * sizeof(float));
    float* m2 = (float*)alloc((size_t)NE_ * HID_ * sizeof(float));
    float* h1 = (float*)alloc((size_t)NV_ * HID_ * sizeof(float));
    float* h2 = (float*)alloc((size_t)NV_ * HID_ * sizeof(float));
    u16* Wt1h = (u16*)alloc((size_t)HID_ * 320 * sizeof(u16));
    u16* Wt1l = (u16*)alloc((size_t)HID_ * 320 * sizeof(u16));
    u16* Wt2h = (u16*)alloc((size_t)HID_ * 256 * sizeof(u16));
    u16* Wt2l = (u16*)alloc((size_t)HID_ * 256 * sizeof(u16));
    float* e  = (float*)alloc((size_t)NV_ * sizeof(float));
    float* watt = (float*)alloc((size_t)NV_ * sizeof(float));
    float* psum = (float*)alloc((size_t)B_ * PCHUNK * D_ * sizeof(float));
    float* pmax = (float*)alloc((size_t)B_ * PCHUNK * D_ * sizeof(float));
    float* p0 = (float*)alloc((size_t)B_ * 2 * D_ * sizeof(float));
    float* p1 = (float*)alloc((size_t)B_ * 2 * HID_ * sizeof(float));
    float* p2 = (float*)alloc((size_t)B_ * 2 * HID_ * sizeof(float));
    // CSR structures
    int* cnt      = (int*)alloc((size_t)SCAN_TOT * sizeof(int));  // [cnt_e|cnt_v|cnt_s]
    int* fill     = (int*)alloc((size_t)SCAN_TOT * sizeof(int));  // same layout
    int* cnt_e = cnt;
    int* cnt_v = cnt + NE_;
    int* cnt_s = cnt + NE_ + NV_;
    int* fill_e = fill;
    int* fill_v = fill + NE_;
    int* fill_s = fill + NE_ + NV_;
    int* rowptr_e = (int*)alloc((size_t)(NE_ + 1) * sizeof(int));
    int* rowptr_v = (int*)alloc((size_t)(NV_ + 1) * sizeof(int));
    int* rowptr_s = (int*)alloc((size_t)(NE_ + 1) * sizeof(int));
    int* bsum  = (int*)alloc((size_t)SCAN_NCH * sizeof(int));
    int* cbase = (int*)alloc((size_t)SCAN_NCH * sizeof(int));
    int*   srcA_e = (int*)  alloc((size_t)NNZ_ * sizeof(int));  // node ids (layer 2)
    int*   srcX_e = (int*)  alloc((size_t)NNZ_ * sizeof(int));  // x[node] ids (layer 1)
    float* val_e  = (float*)alloc((size_t)NNZ_ * sizeof(float));
    int*   srcA_v = (int*)  alloc((size_t)NNZ_ * sizeof(int));
    float* val_v  = (float*)alloc((size_t)NNZ_ * sizeof(float));
    int*   srcA_s = (int*)  alloc((size_t)SNNZ_ * sizeof(int));
    float* val_s  = (float*)alloc((size_t)SNNZ_ * sizeof(float));

    // ---- build CSR ----
    hipMemsetAsync(cnt, 0, (size_t)SCAN_TOT * sizeof(int), stream);
    hist_kernel<<<NNZ_ / 256, 256, 0, stream>>>(inc_cols, NNZ_, cnt_e);
    hist_kernel<<<NNZ_ / 256, 256, 0, stream>>>(inc_rows, NNZ_, cnt_v);
    hist_kernel<<<SNNZ_ / 256, 256, 0, stream>>>(sent_cols, SNNZ_, cnt_s);
    scanA_kernel<<<SCAN_NCH, 256, 0, stream>>>(cnt, bsum);
    scanB_kernel<<<1, 64, 0, stream>>>(bsum, cbase);
    scanC_kernel<<<SCAN_NCH, 256, 0, stream>>>(cnt, cbase, rowptr_e, rowptr_v, rowptr_s, fill);
    place_kernel<<<NNZ_ / 256, 256, 0, stream>>>(inc_cols, inc_rows, inc_vals, NNZ_,
                                                 fill_e, srcA_e, val_e, x, srcX_e);
    place_kernel<<<NNZ_ / 256, 256, 0, stream>>>(inc_rows, inc_cols, inc_vals, NNZ_,
                                                 fill_v, srcA_v, val_v, nullptr, nullptr);
    place_kernel<<<SNNZ_ / 256, 256, 0, stream>>>(sent_cols, sent_rows, sent_vals, SNNZ_,
                                                  fill_s, srcA_s, val_s, nullptr, nullptr);

    // ---- weight conversion (transpose + bf16 hi/lo split) ----
    wconv_kernel<<<(256 * 320 + 255) / 256, 256, 0, stream>>>(W1, D_, 320, Wt1h, Wt1l);
    wconv_kernel<<<(256 * 256 + 255) / 256, 256, 0, stream>>>(W2, HID_, 256, Wt2h, Wt2l);

    // ---- EW = emb @ W1  (vocab-side GEMM; layer-1 linear hoisted before sparse chain)
    {
        dim3 grid((VOCAB + 63) / 64, HID_ / 64);
        gemm_mfma_kernel<false><<<grid, 256, 0, stream>>>(emb, VOCAB, D_, D_,
                                                          Wt1h, Wt1l, 320,
                                                          nullptr, nullptr, EW);
    }

    // ---- layer 1 sparse chain @ dim 256 ----
    gather256_kernel<false><<<NE_ / 4, 256, 0, stream>>>(rowptr_e, srcX_e, val_e,
                                                         EW, deg_e, nullptr, m, NE_);
    gather256_kernel<false><<<NE_ / 4, 256, 0, stream>>>(rowptr_s, srcA_s, val_s,
                                                         m, nullptr, nullptr, m2, NE_);
    gather256_kernel<true><<<NV_ / 4, 256, 0, stream>>>(rowptr_v, srcA_v, val_v,
                                                        m2, deg_v, b1, h1, NV_);

    // ---- layer 2 ----
    gather256_kernel<false><<<NE_ / 4, 256, 0, stream>>>(rowptr_e, srcA_e, val_e,
                                                         h1, deg_e, nullptr, m, NE_);
    gather256_kernel<false><<<NE_ / 4, 256, 0, stream>>>(rowptr_s, srcA_s, val_s,
                                                         m, nullptr, nullptr, m2, NE_);
    gather256_kernel<false><<<NV_ / 4, 256, 0, stream>>>(rowptr_v, srcA_v, val_v,
                                                         m2, nullptr, nullptr, hv, NV_);
    {
        dim3 grid(NV_ / 64, HID_ / 64);
        gemm_mfma_kernel<true><<<grid, 256, 0, stream>>>(hv, NV_, HID_, HID_,
                                                         Wt2h, Wt2l, 256,
                                                         b2, deg_v, h2);
    }

    // ---- pools ----
    dim3 pgrid(B_, PCHUNK);
    logits_kernel<<<NV_ / 4, 256, 0, stream>>>(emb, D_, D_, x, tf_idf, attW0, attb0, e);
    weights_kernel<<<B_, 512, 0, stream>>>(e, watt);
    pool_partial_kernel<<<pgrid, 256, 0, stream>>>(emb, D_, D_, x, watt, psum, pmax);
    pool_combine_kernel<<<B_, 256, 0, stream>>>(psum, pmax, D_, p0);

    logits_kernel<<<NV_ / 4, 256, 0, stream>>>(h1, HID_, HID_, nullptr, tf_idf, attW1, attb1, e);
    weights_kernel<<<B_, 512, 0, stream>>>(e, watt);
    pool_partial_kernel<<<pgrid, 256, 0, stream>>>(h1, HID_, HID_, nullptr, watt, psum, pmax);
    pool_combine_kernel<<<B_, 256, 0, stream>>>(psum, pmax, HID_, p1);

    logits_kernel<<<NV_ / 4, 256, 0, stream>>>(h2, HID_, HID_, nullptr, tf_idf, attW2, attb2, e);
    weights_kernel<<<B_, 512, 0, stream>>>(e, watt);
    pool_partial_kernel<<<pgrid, 256, 0, stream>>>(h2, HID_, HID_, nullptr, watt, psum, pmax);
    pool_combine_kernel<<<B_, 256, 0, stream>>>(psum, pmax, HID_, p2);

    // ---- final linear ----
    final_kernel<<<B_, 256, 0, stream>>>(p0, p1, p2, pW0, pb0, pW1, pb1, pW2, pb2, out);
}

// Round 8
// 362.634 us; speedup vs baseline: 4.0882x; 1.1346x over previous
//
#include <hip/hip_runtime.h>
#include <cstddef>

#define B_   64
#define N_   512
#define NV_  32768
#define NE_  8192
#define NNZ_ 262144
#define SNNZ_ 24576
#define D_   300
#define HID_ 256
#define NC_  10
#define PCHUNK 8
#define PVN (N_ / PCHUNK)   // 64 nodes per pool chunk

#define SCAN_TOT (NE_ + NV_ + NE_)      // 49152 counts, contiguous [cnt_e|cnt_v|cnt_s]
#define SCAN_NCH (SCAN_TOT / 1024)      // 48 chunks
#define SEG1_CH  (NE_ / 1024)           // 8  (start of cnt_v chunks)
#define SEG2_CH  ((NE_ + NV_) / 1024)   // 40 (start of cnt_s chunks)

using u16 = unsigned short;
typedef __attribute__((ext_vector_type(8))) short short8;
typedef __attribute__((ext_vector_type(4))) float f32x4;

__device__ __forceinline__ float bf2f(u16 v) {
    union { unsigned int u; float f; } uf;
    uf.u = ((unsigned int)v) << 16;
    return uf.f;
}
__device__ __forceinline__ u16 f2bf(float f) {
    union { float f; unsigned int u; } uf; uf.f = f;
    unsigned int u = uf.u;
    unsigned int r = u + 0x7fffu + ((u >> 16) & 1u);
    return (u16)(r >> 16);
}

// ---------------- CSR build: histogram -> 3-phase parallel scan -> placement --------
__global__ __launch_bounds__(256) void hist_kernel(const int* __restrict__ keys, int n,
                                                   int* __restrict__ cnt) {
    int i = blockIdx.x * 256 + threadIdx.x;
    if (i < n) atomicAdd(&cnt[keys[i]], 1);
}

__global__ __launch_bounds__(256) void scanA_kernel(const int* __restrict__ cnt,
                                                    int* __restrict__ bsum) {
    int blk = blockIdx.x, t = threadIdx.x;
    int4 v = reinterpret_cast<const int4*>(cnt)[blk * 256 + t];
    int s = v.x + v.y + v.z + v.w;
    __shared__ int red[256];
    red[t] = s;
    __syncthreads();
    for (int o = 128; o > 0; o >>= 1) {
        if (t < o) red[t] += red[t + o];
        __syncthreads();
    }
    if (t == 0) bsum[blk] = red[0];
}

__global__ __launch_bounds__(64) void scanB_kernel(const int* __restrict__ bsum,
                                                   int* __restrict__ cbase) {
    if (threadIdx.x == 0) {
        int run = 0;
        for (int c = 0; c < SCAN_NCH; ++c) {
            if (c == SEG1_CH || c == SEG2_CH) run = 0;
            cbase[c] = run;
            run += bsum[c];
        }
    }
}

__global__ __launch_bounds__(256) void scanC_kernel(const int* __restrict__ cnt,
                                                    const int* __restrict__ cbase,
                                                    int* __restrict__ rowptr_e,
                                                    int* __restrict__ rowptr_v,
                                                    int* __restrict__ rowptr_s,
                                                    int* __restrict__ fill) {
    int blk = blockIdx.x, t = threadIdx.x;
    int gi = blk * 1024 + t * 4;
    int4 v = reinterpret_cast<const int4*>(cnt)[blk * 256 + t];
    int s0 = v.x, s1 = s0 + v.y, s2 = s1 + v.z, s3 = s2 + v.w;
    __shared__ int part[256];
    part[t] = s3;
    __syncthreads();
    for (int o = 1; o < 256; o <<= 1) {
        int a = (t >= o) ? part[t - o] : 0;
        __syncthreads();
        part[t] += a;
        __syncthreads();
    }
    int excl = (t > 0 ? part[t - 1] : 0) + cbase[blk];
    int4 e;
    e.x = excl; e.y = excl + s0; e.z = excl + s1; e.w = excl + s2;
    int* rp; int li;
    if (blk < SEG1_CH)      { rp = rowptr_e; li = gi; }
    else if (blk < SEG2_CH) { rp = rowptr_v; li = gi - NE_; }
    else                    { rp = rowptr_s; li = gi - NE_ - NV_; }
    rp[li + 0] = e.x; rp[li + 1] = e.y; rp[li + 2] = e.z; rp[li + 3] = e.w;
    reinterpret_cast<int4*>(fill)[blk * 256 + t] = e;
    if (t == 255) {
        int tot = excl + s3;
        if (blk == SEG1_CH - 1) rowptr_e[NE_] = tot;
        if (blk == SEG2_CH - 1) rowptr_v[NV_] = tot;
        if (blk == SCAN_NCH - 1) rowptr_s[NE_] = tot;
    }
}

__global__ __launch_bounds__(256) void place_kernel(const int* __restrict__ keys,
                                                    const int* __restrict__ other,
                                                    const float* __restrict__ vals, int n,
                                                    int* __restrict__ fill,
                                                    int* __restrict__ osrc,
                                                    float* __restrict__ oval,
                                                    const int* __restrict__ xmap,
                                                    int* __restrict__ osrc2) {
    int i = blockIdx.x * 256 + threadIdx.x;
    if (i >= n) return;
    int k = keys[i];
    int o = other[i];
    int p = atomicAdd(&fill[k], 1);
    osrc[p] = o;
    oval[p] = vals[i];
    if (osrc2) osrc2[p] = xmap[o];
}

// ---------------- 256-dim segment gather-sum, bf16 src/dst ---------------------------
// dst[seg][:] = gscale[seg] * sum_k vals[k]*src[srcidx[k]][:]   (+bias,relu if EPI)
template <bool EPI>
__global__ __launch_bounds__(256) void gather256_kernel(const int* __restrict__ rowptr,
                                                        const int* __restrict__ srcidx,
                                                        const float* __restrict__ svals,
                                                        const u16* __restrict__ src,
                                                        const float* __restrict__ gscale,
                                                        const float* __restrict__ bias,
                                                        u16* __restrict__ dst, int nseg) {
    int seg = (blockIdx.x * 256 + threadIdx.x) >> 6;
    int lane = threadIdx.x & 63;
    if (seg >= nseg) return;
    int start = rowptr[seg], end = rowptr[seg + 1];
    float4 acc = make_float4(0.f, 0.f, 0.f, 0.f);
    for (int k = start; k < end; ++k) {
        int r = srcidx[k];
        float v = svals[k];
        ushort4 sv = *reinterpret_cast<const ushort4*>(src + (size_t)r * 256 + lane * 4);
        acc.x += v * bf2f(sv.x); acc.y += v * bf2f(sv.y);
        acc.z += v * bf2f(sv.z); acc.w += v * bf2f(sv.w);
    }
    float sc = gscale ? gscale[seg] : 1.f;
    float4 o;
    o.x = sc * acc.x; o.y = sc * acc.y; o.z = sc * acc.z; o.w = sc * acc.w;
    if (EPI) {
        float4 bv = reinterpret_cast<const float4*>(bias)[lane];
        o.x = fmaxf(o.x + bv.x, 0.f); o.y = fmaxf(o.y + bv.y, 0.f);
        o.z = fmaxf(o.z + bv.z, 0.f); o.w = fmaxf(o.w + bv.w, 0.f);
    }
    ushort4 o4;
    o4.x = f2bf(o.x); o4.y = f2bf(o.y); o4.z = f2bf(o.z); o4.w = f2bf(o.w);
    *reinterpret_cast<ushort4*>(dst + (size_t)seg * 256 + lane * 4) = o4;
}

// ---------------- W -> transposed hi/lo bf16 split ----------------------------------
__global__ __launch_bounds__(256) void wconv_kernel(const float* __restrict__ W, int K, int KP,
                                                    u16* __restrict__ Wth, u16* __restrict__ Wtl) {
    int idx = blockIdx.x * 256 + threadIdx.x;
    if (idx >= 256 * KP) return;
    int n = idx & 255;
    int k = idx >> 8;
    float v = (k < K) ? W[(size_t)k * HID_ + n] : 0.f;
    u16 hi = f2bf(v);
    u16 lo = f2bf(v - bf2f(hi));
    Wth[(size_t)n * KP + k] = hi;
    Wtl[(size_t)n * KP + k] = lo;
}

// ---------------- MFMA GEMM, full-N tile 64x256: C = A @ Wt^T -----------------------
// SPLIT_A: A is f32, split hi/lo (3 MFMA); else A is bf16 (2 MFMA).
// CBF16: C stored bf16. EPI: C = relu(degv*acc + bias).
template <bool SPLIT_A, bool EPI, bool CBF16>
__global__ __launch_bounds__(256) void gemm_mfma_kernel(const void* __restrict__ Av,
                                                        int M, int K, int Ks,
                                                        const u16* __restrict__ Bth,
                                                        const u16* __restrict__ Btl, int bstride,
                                                        const float* __restrict__ bias,
                                                        const float* __restrict__ degv,
                                                        void* __restrict__ Cv) {
    __shared__ __align__(16) u16 Ah[64 * 32];
    __shared__ __align__(16) u16 Al[64 * 32];
    __shared__ __align__(16) u16 Bh[256 * 32];
    __shared__ __align__(16) u16 Bl[256 * 32];
    int tid = threadIdx.x;
    int bm0 = blockIdx.x * 64;
    int w = tid >> 6, l = tid & 63;
    int srow = tid >> 2;                 // 0..63
    int skbp = tid & 3;                  // physical k-chunk
    int skbl = skbp ^ ((srow >> 1) & 3); // logical k-chunk (XOR swizzle)
    int arow = bm0 + srow; if (arow >= M) arow = M - 1;
    int sdst = srow * 32 + skbp * 8;
    int frow = w * 16 + (l & 15);
    int akbp = (l >> 4) ^ ((frow >> 1) & 3);

    f32x4 acc[16] = {};
    int nkt = (K + 31) / 32;
    for (int kt = 0; kt < nkt; ++kt) {
        if (kt) __syncthreads();
        int kbase = kt * 32 + skbl * 8;
        // ---- stage A ----
        if constexpr (SPLIT_A) {
            const float* Arow = (const float*)Av + (size_t)arow * Ks;
            float av[8];
            if (kbase + 8 <= K) {
                float4 v0 = *reinterpret_cast<const float4*>(Arow + kbase);
                float4 v1 = *reinterpret_cast<const float4*>(Arow + kbase + 4);
                av[0] = v0.x; av[1] = v0.y; av[2] = v0.z; av[3] = v0.w;
                av[4] = v1.x; av[5] = v1.y; av[6] = v1.z; av[7] = v1.w;
            } else {
#pragma unroll
                for (int e = 0; e < 8; ++e) {
                    int kk = kbase + e;
                    av[e] = (kk < K) ? Arow[kk] : 0.f;
                }
            }
            short8 h8, l8;
#pragma unroll
            for (int e = 0; e < 8; ++e) {
                u16 hi = f2bf(av[e]);
                h8[e] = (short)hi;
                l8[e] = (short)f2bf(av[e] - bf2f(hi));
            }
            *(short8*)&Ah[sdst] = h8;
            *(short8*)&Al[sdst] = l8;
        } else {
            const u16* Arow = (const u16*)Av + (size_t)arow * Ks;
            *(short8*)&Ah[sdst] = *(const short8*)(Arow + kbase);   // K % 32 == 0
        }
        // ---- stage B (all 256 n-rows) ----
#pragma unroll
        for (int i = 0; i < 4; ++i) {
            int br = i * 64 + srow;
            int bkl = skbp ^ ((br >> 1) & 3);
            *(short8*)&Bh[br * 32 + skbp * 8] =
                *(const short8*)(Bth + (size_t)br * bstride + kt * 32 + bkl * 8);
            *(short8*)&Bl[br * 32 + skbp * 8] =
                *(const short8*)(Btl + (size_t)br * bstride + kt * 32 + bkl * 8);
        }
        __syncthreads();
        short8 ah = *(const short8*)&Ah[frow * 32 + akbp * 8];
        short8 al;
        if constexpr (SPLIT_A) al = *(const short8*)&Al[frow * 32 + akbp * 8];
#pragma unroll
        for (int nt = 0; nt < 16; ++nt) {
            int nrow = nt * 16 + (l & 15);
            int bkbp = (l >> 4) ^ ((nrow >> 1) & 3);
            short8 tbh = *(const short8*)&Bh[nrow * 32 + bkbp * 8];
            short8 tbl = *(const short8*)&Bl[nrow * 32 + bkbp * 8];
            acc[nt] = __builtin_amdgcn_mfma_f32_16x16x32_bf16(ah, tbh, acc[nt], 0, 0, 0);
            if constexpr (SPLIT_A)
                acc[nt] = __builtin_amdgcn_mfma_f32_16x16x32_bf16(al, tbh, acc[nt], 0, 0, 0);
            acc[nt] = __builtin_amdgcn_mfma_f32_16x16x32_bf16(ah, tbl, acc[nt], 0, 0, 0);
        }
    }
#pragma unroll
    for (int r = 0; r < 4; ++r) {
        int row = bm0 + w * 16 + (l >> 4) * 4 + r;
        if (row >= M) continue;
        float dv = EPI ? degv[row] : 0.f;
#pragma unroll
        for (int nt = 0; nt < 16; ++nt) {
            int col = nt * 16 + (l & 15);
            float v = acc[nt][r];
            if constexpr (EPI) {
                v = v * dv + bias[col];
                v = v > 0.f ? v : 0.f;
            }
            if constexpr (CBF16) ((u16*)Cv)[(size_t)row * 256 + col] = f2bf(v);
            else                 ((float*)Cv)[(size_t)row * 256 + col] = v;
        }
    }
}

// ---------------- attention logits --------------------------------------------------
template <bool HBF>
__global__ __launch_bounds__(256) void logits_kernel(const void* __restrict__ h, int dim,
                                                     int stride, const int* __restrict__ xidx,
                                                     const float* __restrict__ tfidf,
                                                     const float* __restrict__ attW,
                                                     const float* __restrict__ attb,
                                                     float* __restrict__ e) {
    int w = (blockIdx.x * 256 + threadIdx.x) >> 6;
    int lane = threadIdx.x & 63;
    if (w >= NV_) return;
    int row = xidx ? xidx[w] : w;
    int nq = dim >> 2;
    float s = 0.f;
    if constexpr (HBF) {
        const u16* hp = (const u16*)h + (size_t)row * stride;
        for (int d4 = lane; d4 < nq; d4 += 64) {
            ushort4 a = *reinterpret_cast<const ushort4*>(hp + d4 * 4);
            float4 b = reinterpret_cast<const float4*>(attW)[d4];
            s += bf2f(a.x) * b.x + bf2f(a.y) * b.y + bf2f(a.z) * b.z + bf2f(a.w) * b.w;
        }
    } else {
        const float4* hp = reinterpret_cast<const float4*>((const float*)h + (size_t)row * stride);
        for (int d4 = lane; d4 < nq; d4 += 64) {
            float4 a = hp[d4];
            float4 b = reinterpret_cast<const float4*>(attW)[d4];
            s += a.x * b.x + a.y * b.y + a.z * b.z + a.w * b.w;
        }
    }
#pragma unroll
    for (int off = 32; off > 0; off >>= 1) s += __shfl_down(s, off);
    if (lane == 0) {
        s += tfidf[w * 2] * attW[dim] + tfidf[w * 2 + 1] * attW[dim + 1] + attb[0];
        e[w] = s;
    }
}

// ---------------- pool stage A: per-graph softmax weights ---------------------------
__global__ __launch_bounds__(512) void weights_kernel(const float* __restrict__ e,
                                                      float* __restrict__ w) {
    int b = blockIdx.x;
    int t = threadIdx.x;
    int node = b * N_ + t;
    float ev = e[node];
    __shared__ float red[512];
    red[t] = ev;
    __syncthreads();
    for (int s = 256; s > 0; s >>= 1) {
        if (t < s) red[t] = fmaxf(red[t], red[t + s]);
        __syncthreads();
    }
    float mx = red[0];
    __syncthreads();
    float wv = expf(ev - mx);
    red[t] = wv;
    __syncthreads();
    for (int s = 256; s > 0; s >>= 1) {
        if (t < s) red[t] += red[t + s];
        __syncthreads();
    }
    float inv = 1.f / (red[0] + 1e-10f);
    w[node] = wv * inv;
}

// ---------------- pool stage B: partial weighted-sum + max over 64-node chunks ------
template <bool HBF>
__global__ __launch_bounds__(256) void pool_partial_kernel(const void* __restrict__ h, int dim,
                                                           int stride, const int* __restrict__ xidx,
                                                           const float* __restrict__ w,
                                                           float* __restrict__ psum,
                                                           float* __restrict__ pmax) {
    int b = blockIdx.x, c = blockIdx.y;
    __shared__ int rows[PVN];
    __shared__ float wv[PVN];
    int t = threadIdx.x;
    if (t < PVN) {
        int node = b * N_ + c * PVN + t;
        rows[t] = xidx ? xidx[node] : node;
        wv[t] = w[node];
    }
    __syncthreads();
    float s0 = 0.f, s1 = 0.f, m0 = -3.4e38f, m1 = -3.4e38f;
    int d0 = t, d1 = t + 256;
    bool has1 = d1 < dim;
    for (int i = 0; i < PVN; ++i) {
        float ww = wv[i];
        float x0, x1 = 0.f;
        if constexpr (HBF) {
            const u16* hp = (const u16*)h + (size_t)rows[i] * stride;
            x0 = bf2f(hp[d0]);
            if (has1) x1 = bf2f(hp[d1]);
        } else {
            const float* hp = (const float*)h + (size_t)rows[i] * stride;
            x0 = hp[d0];
            if (has1) x1 = hp[d1];
        }
        s0 += ww * x0;
        m0 = fmaxf(m0, x0);
        if (has1) {
            s1 += ww * x1;
            m1 = fmaxf(m1, x1);
        }
    }
    size_t base = ((size_t)b * PCHUNK + c) * dim;
    psum[base + d0] = s0;
    pmax[base + d0] = m0;
    if (has1) {
        psum[base + d1] = s1;
        pmax[base + d1] = m1;
    }
}

// ---------------- pool stage C: combine chunk partials -------------------------------
__global__ __launch_bounds__(256) void pool_combine_kernel(const float* __restrict__ psum,
                                                           const float* __restrict__ pmax,
                                                           int dim, float* __restrict__ p) {
    int b = blockIdx.x;
    for (int d = threadIdx.x; d < dim; d += 256) {
        float s = 0.f, m = -3.4e38f;
        for (int c = 0; c < PCHUNK; ++c) {
            size_t base = ((size_t)b * PCHUNK + c) * dim;
            s += psum[base + d];
            m = fmaxf(m, pmax[base + d]);
        }
        p[(size_t)b * 2 * dim + d] = s;
        p[(size_t)b * 2 * dim + dim + d] = m;
    }
}

// ---------------- final prediction (parallel GEMV, 256 thr/graph) --------------------
__global__ __launch_bounds__(256) void final_kernel(const float* __restrict__ p0,
                                                    const float* __restrict__ p1,
                                                    const float* __restrict__ p2,
                                                    const float* __restrict__ pW0,
                                                    const float* __restrict__ pb0,
                                                    const float* __restrict__ pW1,
                                                    const float* __restrict__ pb1,
                                                    const float* __restrict__ pW2,
                                                    const float* __restrict__ pb2,
                                                    float* __restrict__ out) {
    int b = blockIdx.x;
    int t = threadIdx.x;
    int lane = t & 63, wv = t >> 6;
    float acc[NC_] = {};
    for (int k = t; k < 2 * D_; k += 256) {
        float pv = p0[(size_t)b * 2 * D_ + k];
        const float* wp = pW0 + (size_t)k * NC_;
#pragma unroll
        for (int c = 0; c < NC_; ++c) acc[c] += pv * wp[c];
    }
    for (int k = t; k < 2 * HID_; k += 256) {
        float pv = p1[(size_t)b * 2 * HID_ + k];
        const float* wp = pW1 + (size_t)k * NC_;
#pragma unroll
        for (int c = 0; c < NC_; ++c) acc[c] += pv * wp[c];
    }
    for (int k = t; k < 2 * HID_; k += 256) {
        float pv = p2[(size_t)b * 2 * HID_ + k];
        const float* wp = pW2 + (size_t)k * NC_;
#pragma unroll
        for (int c = 0; c < NC_; ++c) acc[c] += pv * wp[c];
    }
    __shared__ float red[4][NC_];
#pragma unroll
    for (int c = 0; c < NC_; ++c) {
        float s = acc[c];
#pragma unroll
        for (int off = 32; off > 0; off >>= 1) s += __shfl_down(s, off);
        if (lane == 0) red[wv][c] = s;
    }
    __syncthreads();
    if (t < NC_) {
        float s = red[0][t] + red[1][t] + red[2][t] + red[3][t];
        out[b * NC_ + t] = s + pb0[t] + pb1[t] + pb2[t];
    }
}

extern "C" void kernel_launch(void* const* d_in, const int* in_sizes, int n_in,
                              void* d_out, int out_size, void* d_ws, size_t ws_size,
                              hipStream_t stream) {
    const int*   x         = (const int*)d_in[0];
    const int*   inc_rows  = (const int*)d_in[1];
    const int*   inc_cols  = (const int*)d_in[2];
    const float* inc_vals  = (const float*)d_in[3];
    const int*   sent_rows = (const int*)d_in[4];
    const int*   sent_cols = (const int*)d_in[5];
    const float* sent_vals = (const float*)d_in[6];
    const float* deg_v     = (const float*)d_in[7];
    const float* deg_e     = (const float*)d_in[8];
    const float* tf_idf = (const float*)d_in[11];
    const float* emb    = (const float*)d_in[12];
    const float* W1 = (const float*)d_in[13];
    const float* b1 = (const float*)d_in[14];
    const float* W2 = (const float*)d_in[15];
    const float* b2 = (const float*)d_in[16];
    const float* attW0 = (const float*)d_in[17];
    const float* attb0 = (const float*)d_in[18];
    const float* attW1 = (const float*)d_in[19];
    const float* attb1 = (const float*)d_in[20];
    const float* attW2 = (const float*)d_in[21];
    const float* attb2 = (const float*)d_in[22];
    const float* pW0 = (const float*)d_in[23];
    const float* pb0 = (const float*)d_in[24];
    const float* pW1 = (const float*)d_in[25];
    const float* pb1 = (const float*)d_in[26];
    const float* pW2 = (const float*)d_in[27];
    const float* pb2 = (const float*)d_in[28];
    float* out = (float*)d_out;

    const int VOCAB = 30000;

    // workspace layout
    char* ws = (char*)d_ws;
    size_t off = 0;
    auto alloc = [&](size_t bytes) {
        void* p = ws + off;
        off += (bytes + 255) & ~(size_t)255;
        return p;
    };
    u16* EW = (u16*)alloc((size_t)VOCAB * HID_ * sizeof(u16)); // emb @ W1, bf16
    u16* hv = (u16*)alloc((size_t)NV_ * HID_ * sizeof(u16));
    u16* m  = (u16*)alloc((size_t)NE_ * HID_ * sizeof(u16));
    u16* m2 = (u16*)alloc((size_t)NE_ * HID_ * sizeof(u16));
    u16* h1 = (u16*)alloc((size_t)NV_ * HID_ * sizeof(u16));
    u16* h2 = (u16*)alloc((size_t)NV_ * HID_ * sizeof(u16));
    u16* Wt1h = (u16*)alloc((size_t)HID_ * 320 * sizeof(u16));
    u16* Wt1l = (u16*)alloc((size_t)HID_ * 320 * sizeof(u16));
    u16* Wt2h = (u16*)alloc((size_t)HID_ * 256 * sizeof(u16));
    u16* Wt2l = (u16*)alloc((size_t)HID_ * 256 * sizeof(u16));
    float* e  = (float*)alloc((size_t)NV_ * sizeof(float));
    float* watt = (float*)alloc((size_t)NV_ * sizeof(float));
    float* psum = (float*)alloc((size_t)B_ * PCHUNK * D_ * sizeof(float));
    float* pmax = (float*)alloc((size_t)B_ * PCHUNK * D_ * sizeof(float));
    float* p0 = (float*)alloc((size_t)B_ * 2 * D_ * sizeof(float));
    float* p1 = (float*)alloc((size_t)B_ * 2 * HID_ * sizeof(float));
    float* p2 = (float*)alloc((size_t)B_ * 2 * HID_ * sizeof(float));
    // CSR structures
    int* cnt      = (int*)alloc((size_t)SCAN_TOT * sizeof(int));  // [cnt_e|cnt_v|cnt_s]
    int* fill     = (int*)alloc((size_t)SCAN_TOT * sizeof(int));  // same layout
    int* cnt_e = cnt;
    int* cnt_v = cnt + NE_;
    int* cnt_s = cnt + NE_ + NV_;
    int* fill_e = fill;
    int* fill_v = fill + NE_;
    int* fill_s = fill + NE_ + NV_;
    int* rowptr_e = (int*)alloc((size_t)(NE_ + 1) * sizeof(int));
    int* rowptr_v = (int*)alloc((size_t)(NV_ + 1) * sizeof(int));
    int* rowptr_s = (int*)alloc((size_t)(NE_ + 1) * sizeof(int));
    int* bsum  = (int*)alloc((size_t)SCAN_NCH * sizeof(int));
    int* cbase = (int*)alloc((size_t)SCAN_NCH * sizeof(int));
    int*   srcA_e = (int*)  alloc((size_t)NNZ_ * sizeof(int));  // node ids (layer 2)
    int*   srcX_e = (int*)  alloc((size_t)NNZ_ * sizeof(int));  // x[node] ids (layer 1)
    float* val_e  = (float*)alloc((size_t)NNZ_ * sizeof(float));
    int*   srcA_v = (int*)  alloc((size_t)NNZ_ * sizeof(int));
    float* val_v  = (float*)alloc((size_t)NNZ_ * sizeof(float));
    int*   srcA_s = (int*)  alloc((size_t)SNNZ_ * sizeof(int));
    float* val_s  = (float*)alloc((size_t)SNNZ_ * sizeof(float));

    // ---- build CSR ----
    hipMemsetAsync(cnt, 0, (size_t)SCAN_TOT * sizeof(int), stream);
    hist_kernel<<<NNZ_ / 256, 256, 0, stream>>>(inc_cols, NNZ_, cnt_e);
    hist_kernel<<<NNZ_ / 256, 256, 0, stream>>>(inc_rows, NNZ_, cnt_v);
    hist_kernel<<<SNNZ_ / 256, 256, 0, stream>>>(sent_cols, SNNZ_, cnt_s);
    scanA_kernel<<<SCAN_NCH, 256, 0, stream>>>(cnt, bsum);
    scanB_kernel<<<1, 64, 0, stream>>>(bsum, cbase);
    scanC_kernel<<<SCAN_NCH, 256, 0, stream>>>(cnt, cbase, rowptr_e, rowptr_v, rowptr_s, fill);
    place_kernel<<<NNZ_ / 256, 256, 0, stream>>>(inc_cols, inc_rows, inc_vals, NNZ_,
                                                 fill_e, srcA_e, val_e, x, srcX_e);
    place_kernel<<<NNZ_ / 256, 256, 0, stream>>>(inc_rows, inc_cols, inc_vals, NNZ_,
                                                 fill_v, srcA_v, val_v, nullptr, nullptr);
    place_kernel<<<SNNZ_ / 256, 256, 0, stream>>>(sent_cols, sent_rows, sent_vals, SNNZ_,
                                                  fill_s, srcA_s, val_s, nullptr, nullptr);

    // ---- weight conversion (transpose + bf16 hi/lo split) ----
    wconv_kernel<<<(256 * 320 + 255) / 256, 256, 0, stream>>>(W1, D_, 320, Wt1h, Wt1l);
    wconv_kernel<<<(256 * 256 + 255) / 256, 256, 0, stream>>>(W2, HID_, 256, Wt2h, Wt2l);

    // ---- EW = emb @ W1 (f32 A hi/lo split; bf16 out; A read once, full-N tile) ----
    gemm_mfma_kernel<true, false, true><<<(VOCAB + 63) / 64, 256, 0, stream>>>(
        emb, VOCAB, D_, D_, Wt1h, Wt1l, 320, nullptr, nullptr, EW);

    // ---- layer 1 sparse chain @ dim 256 (all bf16) ----
    gather256_kernel<false><<<NE_ / 4, 256, 0, stream>>>(rowptr_e, srcX_e, val_e,
                                                         EW, deg_e, nullptr, m, NE_);
    gather256_kernel<false><<<NE_ / 4, 256, 0, stream>>>(rowptr_s, srcA_s, val_s,
                                                         m, nullptr, nullptr, m2, NE_);
    gather256_kernel<true><<<NV_ / 4, 256, 0, stream>>>(rowptr_v, srcA_v, val_v,
                                                        m2, deg_v, b1, h1, NV_);

    // ---- layer 2 ----
    gather256_kernel<false><<<NE_ / 4, 256, 0, stream>>>(rowptr_e, srcA_e, val_e,
                                                         h1, deg_e, nullptr, m, NE_);
    gather256_kernel<false><<<NE_ / 4, 256, 0, stream>>>(rowptr_s, srcA_s, val_s,
                                                         m, nullptr, nullptr, m2, NE_);
    gather256_kernel<false><<<NV_ / 4, 256, 0, stream>>>(rowptr_v, srcA_v, val_v,
                                                         m2, nullptr, nullptr, hv, NV_);
    // h2 = relu(degv * hv@W2 + b2)  (bf16 A, 2-MFMA; bf16 out)
    gemm_mfma_kernel<false, true, true><<<NV_ / 64, 256, 0, stream>>>(
        hv, NV_, HID_, HID_, Wt2h, Wt2l, 256, b2, deg_v, h2);

    // ---- pools ----
    dim3 pgrid(B_, PCHUNK);
    logits_kernel<false><<<NV_ / 4, 256, 0, stream>>>(emb, D_, D_, x, tf_idf, attW0, attb0, e);
    weights_kernel<<<B_, 512, 0, stream>>>(e, watt);
    pool_partial_kernel<false><<<pgrid, 256, 0, stream>>>(emb, D_, D_, x, watt, psum, pmax);
    pool_combine_kernel<<<B_, 256, 0, stream>>>(psum, pmax, D_, p0);

    logits_kernel<true><<<NV_ / 4, 256, 0, stream>>>(h1, HID_, HID_, nullptr, tf_idf, attW1, attb1, e);
    weights_kernel<<<B_, 512, 0, stream>>>(e, watt);
    pool_partial_kernel<true><<<pgrid, 256, 0, stream>>>(h1, HID_, HID_, nullptr, watt, psum, pmax);
    pool_combine_kernel<<<B_, 256, 0, stream>>>(psum, pmax, HID_, p1);

    logits_kernel<true><<<NV_ / 4, 256, 0, stream>>>(h2, HID_, HID_, nullptr, tf_idf, attW2, attb2, e);
    weights_kernel<<<B_, 512, 0, stream>>>(e, watt);
    pool_partial_kernel<true><<<pgrid, 256, 0, stream>>>(h2, HID_, HID_, nullptr, watt, psum, pmax);
    pool_combine_kernel<<<B_, 256, 0, stream>>>(psum, pmax, HID_, p2);

    // ---- final linear ----
    final_kernel<<<B_, 256, 0, stream>>>(p0, p1, p2, pW0, pb0, pW1, pb1, pW2, pb2, out);
}